// Round 2
// baseline (6958.541 us; speedup 1.0000x reference)
//
#include <hip/hip_runtime.h>
#include <hip/hip_bf16.h>

typedef __hip_bfloat16 bf16;

__device__ __forceinline__ float b2f(bf16 v) { return __bfloat162float(v); }
__device__ __forceinline__ bf16  f2b(float v) { return __float2bfloat16(v); }

__device__ __forceinline__ float ldf(const bf16* p)  { return __bfloat162float(*p); }
__device__ __forceinline__ float ldf(const float* p) { return *p; }
__device__ __forceinline__ void  stf(bf16* p, float v)  { *p = __float2bfloat16(v); }
__device__ __forceinline__ void  stf(float* p, float v) { *p = v; }

// ---------------------------------------------------------------------------
// LayerNorm over last dim C=1024. One block (256 threads) per row.
// Input fp32, params fp32, output bf16.
// ---------------------------------------------------------------------------
__global__ __launch_bounds__(256) void ln_kernel(const float* __restrict__ x,
                                                 const float* __restrict__ g,
                                                 const float* __restrict__ b,
                                                 bf16* __restrict__ out)
{
    const int C = 1024;
    int row = blockIdx.x;
    int tid = threadIdx.x;
    const float* xr = x + (size_t)row * C;

    float v[4];
    float s = 0.f, s2 = 0.f;
#pragma unroll
    for (int i = 0; i < 4; ++i) {
        float f = xr[tid + i * 256];
        v[i] = f;
        s += f;
        s2 += f * f;
    }
    // wave (64-lane) reduction
#pragma unroll
    for (int off = 32; off > 0; off >>= 1) {
        s  += __shfl_down(s,  off, 64);
        s2 += __shfl_down(s2, off, 64);
    }
    __shared__ float red[8];
    int wave = tid >> 6;
    if ((tid & 63) == 0) { red[wave] = s; red[wave + 4] = s2; }
    __syncthreads();
    float ts  = red[0] + red[1] + red[2] + red[3];
    float ts2 = red[4] + red[5] + red[6] + red[7];
    float mu  = ts * (1.f / 1024.f);
    float var = ts2 * (1.f / 1024.f) - mu * mu;
    float rstd = rsqrtf(var + 1e-5f);
#pragma unroll
    for (int i = 0; i < 4; ++i) {
        int c = tid + i * 256;
        out[(size_t)row * C + c] = f2b((v[i] - mu) * rstd * g[c] + b[c]);
    }
}

// ---------------------------------------------------------------------------
// Tiled fp32 GEMM: C[M,N] (+bias[n]) (+res[m,n]) (ReLU) = A[M,K] @ B[K,N]
// A bf16 row-major, B fp32 (weights) row-major. 64x64 tile, BK=16,
// 256 threads, 4x4 per thread. blockIdx.z: head batching.
// ---------------------------------------------------------------------------
template<bool RELU, bool HAS_BIAS, bool HAS_RES, typename ResT, typename OutT>
__global__ __launch_bounds__(256) void gemm_kernel(
    const bf16* __restrict__ A, int lda,
    const float* __restrict__ Bm, int ldb, long b_zstride,
    const float* __restrict__ bias,
    const ResT* __restrict__ res, int ldr,
    OutT* __restrict__ Cm, int ldc, int c_zoff,
    int M, int N, int K)
{
    __shared__ __align__(16) float As[16][68];
    __shared__ __align__(16) float Bs[16][68];

    int tid = threadIdx.x;
    int tx = tid & 15, ty = tid >> 4;
    int bn0 = blockIdx.x * 64;
    int bm0 = blockIdx.y * 64;
    const float* Bz = Bm + (long)blockIdx.z * b_zstride;

    float acc[4][4] = {};

    int am = tid >> 2;            // A-load row within tile (0..63)
    int ak = (tid & 3) * 4;       // A-load k within tile
    int bk = tid >> 4;            // B-load k within tile (0..15)
    int bn = (tid & 15) * 4;      // B-load col within tile

    for (int k0 = 0; k0 < K; k0 += 16) {
        const bf16* Ap = A + (size_t)(bm0 + am) * lda + k0 + ak;
#pragma unroll
        for (int j = 0; j < 4; ++j) As[ak + j][am] = b2f(Ap[j]);
        const float* Bp = Bz + (size_t)(k0 + bk) * ldb + bn0 + bn;
#pragma unroll
        for (int j = 0; j < 4; ++j) Bs[bk][bn + j] = Bp[j];
        __syncthreads();
#pragma unroll
        for (int kk = 0; kk < 16; ++kk) {
            float4 a4 = *(const float4*)&As[kk][ty * 4];
            float4 b4 = *(const float4*)&Bs[kk][tx * 4];
            float a[4] = {a4.x, a4.y, a4.z, a4.w};
            float bb[4] = {b4.x, b4.y, b4.z, b4.w};
#pragma unroll
            for (int i = 0; i < 4; ++i)
#pragma unroll
                for (int j = 0; j < 4; ++j)
                    acc[i][j] += a[i] * bb[j];
        }
        __syncthreads();
    }

#pragma unroll
    for (int i = 0; i < 4; ++i) {
        int gm = bm0 + ty * 4 + i;
#pragma unroll
        for (int j = 0; j < 4; ++j) {
            int gn = bn0 + tx * 4 + j;
            float v = acc[i][j];
            if (HAS_BIAS) v += bias[gn];
            if (HAS_RES)  v += ldf(res + (size_t)gm * ldr + gn);
            if (RELU)     v = fmaxf(v, 0.f);
            stf(Cm + (size_t)blockIdx.z * c_zoff + (size_t)gm * ldc + gn, v);
        }
    }
}

// ---------------------------------------------------------------------------
// Causal flash attention, fp32 compute, bf16 in/out.
// Grid (T/64, H, B), 256 threads. Thread (r = tid>>2, quarter = tid&3)
// owns S/P columns q*16..+15 and O dims q*16..+15 of row r.
// ---------------------------------------------------------------------------
__global__ __launch_bounds__(256) void attn_kernel(
    const bf16* __restrict__ q, const bf16* __restrict__ k,
    const bf16* __restrict__ v, bf16* __restrict__ o, int T)
{
    const int C = 1024;
    int qt = blockIdx.x, h = blockIdx.y, b = blockIdx.z;
    int tid = threadIdx.x;
    int r  = tid >> 2;
    int c0 = (tid & 3) * 16;

    __shared__ float Qs[64][65];
    __shared__ float Ks[64][65];
    __shared__ float Vs[64][65];
    __shared__ float Ps[64][65];

    size_t qbase = ((size_t)(b * T + qt * 64 + r)) * C + h * 64;
#pragma unroll
    for (int j = 0; j < 16; ++j) Qs[r][c0 + j] = b2f(q[qbase + c0 + j]);

    float m = -1e30f, l = 0.f;
    float acc[16];
#pragma unroll
    for (int d = 0; d < 16; ++d) acc[d] = 0.f;
    const float scale = 0.125f;  // 1/sqrt(64)
    int qrow = qt * 64 + r;

    for (int kt = 0; kt <= qt; ++kt) {
        size_t kb = ((size_t)(b * T + kt * 64 + r)) * C + h * 64;
#pragma unroll
        for (int j = 0; j < 16; ++j) {
            Ks[r][c0 + j] = b2f(k[kb + c0 + j]);
            Vs[r][c0 + j] = b2f(v[kb + c0 + j]);
        }
        __syncthreads();

        float sv[16];
#pragma unroll
        for (int c = 0; c < 16; ++c) {
            float a = 0.f;
#pragma unroll
            for (int kk = 0; kk < 64; ++kk) a += Qs[r][kk] * Ks[c0 + c][kk];
            a *= scale;
            if (kt * 64 + c0 + c > qrow) a = -1e30f;
            sv[c] = a;
        }
        float mx = sv[0];
#pragma unroll
        for (int c = 1; c < 16; ++c) mx = fmaxf(mx, sv[c]);
        mx = fmaxf(mx, __shfl_xor(mx, 1, 4));
        mx = fmaxf(mx, __shfl_xor(mx, 2, 4));
        float mn = fmaxf(m, mx);
        float alpha = __expf(m - mn);
        float ps = 0.f;
#pragma unroll
        for (int c = 0; c < 16; ++c) {
            float p = __expf(sv[c] - mn);
            Ps[r][c0 + c] = p;
            ps += p;
        }
        ps += __shfl_xor(ps, 1, 4);
        ps += __shfl_xor(ps, 2, 4);
        l = l * alpha + ps;
        m = mn;
#pragma unroll
        for (int d = 0; d < 16; ++d) acc[d] *= alpha;
        __syncthreads();   // Ps visible to whole block

        for (int s = 0; s < 64; ++s) {
            float p = Ps[r][s];
#pragma unroll
            for (int d = 0; d < 16; ++d) acc[d] += p * Vs[s][c0 + d];
        }
        __syncthreads();   // done with Ks/Vs/Ps before next tile
    }

    float inv = 1.f / l;
#pragma unroll
    for (int d = 0; d < 16; ++d)
        o[qbase + c0 + d] = f2b(acc[d] * inv);
}

// ---------------------------------------------------------------------------
extern "C" void kernel_launch(void* const* d_in, const int* in_sizes, int n_in,
                              void* d_out, int out_size, void* d_ws, size_t ws_size,
                              hipStream_t stream)
{
    // Reference dtypes: ALL float32 (per setup_inputs / reference return).
    const float* x   = (const float*)d_in[0];
    const float* Wq  = (const float*)d_in[1];
    const float* Wk  = (const float*)d_in[2];
    const float* Wv  = (const float*)d_in[3];
    const float* Wo  = (const float*)d_in[4];
    const float* bo  = (const float*)d_in[5];
    const float* g1  = (const float*)d_in[6];
    const float* be1 = (const float*)d_in[7];
    const float* g2  = (const float*)d_in[8];
    const float* be2 = (const float*)d_in[9];
    const float* W1  = (const float*)d_in[10];
    const float* b1  = (const float*)d_in[11];
    const float* W2  = (const float*)d_in[12];
    const float* b2  = (const float*)d_in[13];

    const int Bd = 4, T = 2048, C = 1024, H = 16;
    const int M = Bd * T;  // 8192

    char* ws = (char*)d_ws;
    bf16*  xn   = (bf16*)(ws + 0);                      // 16 MB  [M,C] bf16
    bf16*  qb   = (bf16*)(ws + (16ull << 20));          // 16 MB
    bf16*  kb   = (bf16*)(ws + (32ull << 20));          // 16 MB
    bf16*  vb   = (bf16*)(ws + (48ull << 20));          // 16 MB
    bf16*  attn = (bf16*)(ws + 0);                      // reuse xn (dead after QKV)
    float* x1   = (float*)(ws + (64ull << 20));         // 32 MB  [M,C] fp32
    bf16*  xn2  = (bf16*)(ws + (96ull << 20));          // 16 MB
    bf16*  hb   = (bf16*)(ws + 0);                      // 64 MB, reuse xn/q/k/v (dead)

    dim3 blk(256);

    // LN1: xn = ln(x; g1, be1)   (bf16 out)
    ln_kernel<<<M, blk, 0, stream>>>(x, g1, be1, xn);

    // QKV projections, head-batched over z (Wq[h] is [C,64] row-major fp32)
    gemm_kernel<false, false, false, float, bf16><<<dim3(1, 128, 16), blk, 0, stream>>>(
        xn, C, Wq, 64, (long)C * 64, nullptr, nullptr, 0, qb, C, 64, M, 64, C);
    gemm_kernel<false, false, false, float, bf16><<<dim3(1, 128, 16), blk, 0, stream>>>(
        xn, C, Wk, 64, (long)C * 64, nullptr, nullptr, 0, kb, C, 64, M, 64, C);
    gemm_kernel<false, false, false, float, bf16><<<dim3(1, 128, 16), blk, 0, stream>>>(
        xn, C, Wv, 64, (long)C * 64, nullptr, nullptr, 0, vb, C, 64, M, 64, C);

    // causal attention
    attn_kernel<<<dim3(T / 64, H, Bd), blk, 0, stream>>>(qb, kb, vb, attn, T);

    // x1 = x + attn @ Wo + bo   (fp32 out)
    gemm_kernel<false, true, true, float, float><<<dim3(16, 128, 1), blk, 0, stream>>>(
        attn, C, Wo, C, 0, bo, x, C, x1, C, 0, M, C, C);

    // LN2: xn2 = ln(x1; g2, be2)
    ln_kernel<<<M, blk, 0, stream>>>(x1, g2, be2, xn2);

    // h = relu(xn2 @ W1 + b1)   (bf16 out)
    gemm_kernel<true, true, false, float, bf16><<<dim3(64, 128, 1), blk, 0, stream>>>(
        xn2, C, W1, 4 * C, 0, b1, nullptr, 0, hb, 4 * C, 0, M, 4 * C, C);

    // out = x1 + h @ W2 + b2   (fp32 out, final)
    gemm_kernel<false, true, true, float, float><<<dim3(16, 128, 1), blk, 0, stream>>>(
        hb, 4 * C, W2, C, 0, b2, x1, C, (float*)d_out, C, 0, M, C, 4 * C);
}

// Round 3
// 781.154 us; speedup vs baseline: 8.9080x; 8.9080x over previous
//
#include <hip/hip_runtime.h>
#include <hip/hip_bf16.h>

typedef __hip_bfloat16 bf16;
typedef __attribute__((ext_vector_type(8))) short bf16x8;
typedef __attribute__((ext_vector_type(4))) float f32x4;

__device__ __forceinline__ float b2f(bf16 v) { return __bfloat162float(v); }
__device__ __forceinline__ bf16  f2b(float v) { return __float2bfloat16(v); }
__device__ __forceinline__ float ldf(const bf16* p)  { return __bfloat162float(*p); }
__device__ __forceinline__ float ldf(const float* p) { return *p; }
__device__ __forceinline__ void  stf(bf16* p, float v)  { *p = __float2bfloat16(v); }
__device__ __forceinline__ void  stf(float* p, float v) { *p = v; }

// async global->LDS, 16 B per lane; LDS dest = wave-uniform base + lane*16
__device__ __forceinline__ void load_lds16(const bf16* g, short* lds) {
    __builtin_amdgcn_global_load_lds(
        (const __attribute__((address_space(1))) unsigned int*)g,
        (__attribute__((address_space(3))) unsigned int*)lds, 16, 0, 0);
}

// ---------------------------------------------------------------------------
// LayerNorm over last dim C=1024. One block (256 threads) per row. bf16 out.
// ---------------------------------------------------------------------------
__global__ __launch_bounds__(256) void ln_kernel(const float* __restrict__ x,
                                                 const float* __restrict__ g,
                                                 const float* __restrict__ b,
                                                 bf16* __restrict__ out)
{
    const int C = 1024;
    int row = blockIdx.x;
    int tid = threadIdx.x;
    const float* xr = x + (size_t)row * C;

    float v[4];
    float s = 0.f, s2 = 0.f;
#pragma unroll
    for (int i = 0; i < 4; ++i) {
        float f = xr[tid + i * 256];
        v[i] = f; s += f; s2 += f * f;
    }
#pragma unroll
    for (int off = 32; off > 0; off >>= 1) {
        s  += __shfl_down(s,  off, 64);
        s2 += __shfl_down(s2, off, 64);
    }
    __shared__ float red[8];
    int wave = tid >> 6;
    if ((tid & 63) == 0) { red[wave] = s; red[wave + 4] = s2; }
    __syncthreads();
    float ts  = red[0] + red[1] + red[2] + red[3];
    float ts2 = red[4] + red[5] + red[6] + red[7];
    float mu  = ts * (1.f / 1024.f);
    float var = ts2 * (1.f / 1024.f) - mu * mu;
    float rstd = rsqrtf(var + 1e-5f);
#pragma unroll
    for (int i = 0; i < 4; ++i) {
        int c = tid + i * 256;
        out[(size_t)row * C + c] = f2b((v[i] - mu) * rstd * g[c] + b[c]);
    }
}

// ---------------------------------------------------------------------------
// Tiled transpose + convert to bf16: out[n][k] = in[k][n].  32x32 LDS tiles.
// grid: (cols/32, rows/32, z). in += z*in_zoff (elements), out += z*out_zoff.
// ---------------------------------------------------------------------------
template<typename InT>
__global__ __launch_bounds__(256) void transpose_cvt(
    const InT* __restrict__ in, long in_zoff, int in_ld,
    bf16* __restrict__ out, long out_zoff, int out_ld)
{
    __shared__ float t[32][33];
    int tx = threadIdx.x & 31, ty = threadIdx.x >> 5;  // 32 x 8
    const InT* ip = in + (size_t)blockIdx.z * in_zoff;
    bf16* op = out + (size_t)blockIdx.z * out_zoff;
    int n0 = blockIdx.x * 32, k0 = blockIdx.y * 32;
#pragma unroll
    for (int i = 0; i < 4; ++i)
        t[ty + i * 8][tx] = ldf(ip + (size_t)(k0 + ty + i * 8) * in_ld + n0 + tx);
    __syncthreads();
#pragma unroll
    for (int i = 0; i < 4; ++i)
        op[(size_t)(n0 + ty + i * 8) * out_ld + k0 + tx] = f2b(t[tx][ty + i * 8]);
}

// ---------------------------------------------------------------------------
// MFMA GEMM (m97 structure): C[M,N] = A[M,K] @ B[K,N], B given TRANSPOSED
// (Bt[n][k], ld=ldb). 128x128 tile, BK=32, 256 thr = 4 waves, each wave a
// 64x64 quadrant via 4x4 frags of 16x16x32. global_load_lds width-16 staging.
// ---------------------------------------------------------------------------
template<bool RELU, bool HAS_BIAS, bool HAS_RES, typename ResT, typename OutT>
__global__ __launch_bounds__(256) void gemm_bt(
    const bf16* __restrict__ A, int lda,
    const bf16* __restrict__ Bt, int ldb,
    const float* __restrict__ bias,
    const ResT* __restrict__ res, int ldr,
    OutT* __restrict__ Cm, int ldc,
    int M, int N, int K)
{
    __shared__ short As[128 * 32];
    __shared__ short Bs[128 * 32];
    int tid = threadIdx.x, wv = tid >> 6, ln = tid & 63;
    int bm0 = blockIdx.y * 128, bn0 = blockIdx.x * 128;
    int wm = (wv & 1) * 64, wn = (wv >> 1) * 64;
    int quad = ln >> 4, lane15 = ln & 15;

    f32x4 acc[4][4] = {};

    int srow = ln >> 2;          // row within 16-row staging chunk
    int scol = (ln & 3) * 8;     // k element offset
    const bf16* Ab = A + (size_t)bm0 * lda;
    const bf16* Bb = Bt + (size_t)bn0 * ldb;

    for (int k0 = 0; k0 < K; k0 += 32) {
#pragma unroll
        for (int i = 0; i < 2; ++i) {
            int ch = wv + i * 4;   // 8 chunks of 16 rows
            load_lds16(Ab + (size_t)(ch * 16 + srow) * lda + k0 + scol, &As[ch * 16 * 32]);
            load_lds16(Bb + (size_t)(ch * 16 + srow) * ldb + k0 + scol, &Bs[ch * 16 * 32]);
        }
        __syncthreads();
        bf16x8 af[4], bfr[4];
#pragma unroll
        for (int mi = 0; mi < 4; ++mi)
            af[mi] = *(const bf16x8*)&As[(wm + mi * 16 + lane15) * 32 + quad * 8];
#pragma unroll
        for (int ni = 0; ni < 4; ++ni)
            bfr[ni] = *(const bf16x8*)&Bs[(wn + ni * 16 + lane15) * 32 + quad * 8];
#pragma unroll
        for (int mi = 0; mi < 4; ++mi)
#pragma unroll
            for (int ni = 0; ni < 4; ++ni)
                acc[mi][ni] = __builtin_amdgcn_mfma_f32_16x16x32_bf16(
                    af[mi], bfr[ni], acc[mi][ni], 0, 0, 0);
        __syncthreads();
    }

#pragma unroll
    for (int mi = 0; mi < 4; ++mi) {
#pragma unroll
        for (int r = 0; r < 4; ++r) {
            int gm = bm0 + wm + mi * 16 + quad * 4 + r;
#pragma unroll
            for (int ni = 0; ni < 4; ++ni) {
                int gn = bn0 + wn + ni * 16 + lane15;
                float v = acc[mi][ni][r];
                if (HAS_BIAS) v += bias[gn];
                if (HAS_RES)  v += ldf(res + (size_t)gm * ldr + gn);
                if (RELU)     v = fmaxf(v, 0.f);
                stf(Cm + (size_t)gm * ldc + gn, v);
            }
        }
    }
}

// ---------------------------------------------------------------------------
// MFMA causal flash attention. Grid (T/64, H, B), 256 thr = 4 waves.
// qkv: [M][3072] bf16 (q|k|v, head-major cols). vt: [b][h][64 d][T] bf16.
// Block: 64 q-rows (16/wave). Per k-tile (64 keys): QK^T (8 MFMA) ->
// online softmax -> P to per-wave LDS (A-layout round-trip) -> PV (8 MFMA).
// ---------------------------------------------------------------------------
__global__ __launch_bounds__(256) void attn_kernel(
    const bf16* __restrict__ qkv, const bf16* __restrict__ vt,
    bf16* __restrict__ o, int T)
{
    const int LDQ = 3072;
    int qt = blockIdx.x, h = blockIdx.y, b = blockIdx.z;
    int tid = threadIdx.x, wv = tid >> 6, ln = tid & 63;
    int quad = ln >> 4, lane15 = ln & 15;

    __shared__ short Qs[64 * 64];     // [qrow][d]
    __shared__ short Ks[64 * 64];     // [key][d]
    __shared__ short Vs[64 * 64];     // [d][key]  (from global V^T)
    __shared__ short Ps[4][16 * 64];  // per-wave [qrow16][key]

    int lr = ln >> 3;          // row within 8-row staging chunk
    int lc = (ln & 7) * 8;     // col element offset

#pragma unroll
    for (int i = 0; i < 2; ++i) {
        int ch = wv * 2 + i;
        load_lds16(qkv + (size_t)(b * T + qt * 64 + ch * 8 + lr) * LDQ + h * 64 + lc,
                   &Qs[ch * 8 * 64]);
    }

    f32x4 oacc[4] = {};
    float mrow[4], lrow[4];
#pragma unroll
    for (int r = 0; r < 4; ++r) { mrow[r] = -3e38f; lrow[r] = 0.f; }
    const float scale = 0.125f;  // 1/sqrt(64)

    for (int kt = 0; kt <= qt; ++kt) {
        __syncthreads();   // prev-iter LDS reads done (also Q staging drain at kt=0)
#pragma unroll
        for (int i = 0; i < 2; ++i) {
            int ch = wv * 2 + i;
            load_lds16(qkv + (size_t)(b * T + kt * 64 + ch * 8 + lr) * LDQ + 1024 + h * 64 + lc,
                       &Ks[ch * 8 * 64]);
            load_lds16(vt + ((size_t)((b * 16 + h) * 64 + ch * 8 + lr)) * T + kt * 64 + lc,
                       &Vs[ch * 8 * 64]);
        }
        __syncthreads();

        // S = Q K^T  (wave's 16 rows x 64 keys)
        f32x4 sacc[4] = {};
#pragma unroll
        for (int ks = 0; ks < 2; ++ks) {
            bf16x8 a = *(const bf16x8*)&Qs[(wv * 16 + lane15) * 64 + ks * 32 + quad * 8];
#pragma unroll
            for (int ni = 0; ni < 4; ++ni) {
                bf16x8 bb = *(const bf16x8*)&Ks[(ni * 16 + lane15) * 64 + ks * 32 + quad * 8];
                sacc[ni] = __builtin_amdgcn_mfma_f32_16x16x32_bf16(a, bb, sacc[ni], 0, 0, 0);
            }
        }

        // online softmax (row = quad*4+r, cols spread over lane15 x ni)
        float p[4][4];
#pragma unroll
        for (int r = 0; r < 4; ++r) {
            int qrow = qt * 64 + wv * 16 + quad * 4 + r;
            float mx = -3e38f;
#pragma unroll
            for (int ni = 0; ni < 4; ++ni) {
                float s = sacc[ni][r] * scale;
                if (kt * 64 + ni * 16 + lane15 > qrow) s = -3e38f;
                p[ni][r] = s;
                mx = fmaxf(mx, s);
            }
            mx = fmaxf(mx, __shfl_xor(mx, 1, 64));
            mx = fmaxf(mx, __shfl_xor(mx, 2, 64));
            mx = fmaxf(mx, __shfl_xor(mx, 4, 64));
            mx = fmaxf(mx, __shfl_xor(mx, 8, 64));
            float mn = fmaxf(mrow[r], mx);
            float alpha = __expf(mrow[r] - mn);
            float ps = 0.f;
#pragma unroll
            for (int ni = 0; ni < 4; ++ni) {
                float pe = __expf(p[ni][r] - mn);
                p[ni][r] = pe;
                ps += pe;
            }
            ps += __shfl_xor(ps, 1, 64);
            ps += __shfl_xor(ps, 2, 64);
            ps += __shfl_xor(ps, 4, 64);
            ps += __shfl_xor(ps, 8, 64);
            lrow[r] = lrow[r] * alpha + ps;
            mrow[r] = mn;
#pragma unroll
            for (int di = 0; di < 4; ++di) oacc[di][r] *= alpha;
        }

        // P: C-layout regs -> per-wave LDS (bf16) for A-layout read-back
#pragma unroll
        for (int r = 0; r < 4; ++r)
#pragma unroll
            for (int ni = 0; ni < 4; ++ni) {
                bf16 pb = f2b(p[ni][r]);
                Ps[wv][(quad * 4 + r) * 64 + ni * 16 + lane15] = *(short*)&pb;
            }
        __syncthreads();

        // O += P V
#pragma unroll
        for (int ks = 0; ks < 2; ++ks) {
            bf16x8 a = *(const bf16x8*)&Ps[wv][lane15 * 64 + ks * 32 + quad * 8];
#pragma unroll
            for (int di = 0; di < 4; ++di) {
                bf16x8 bb = *(const bf16x8*)&Vs[(di * 16 + lane15) * 64 + ks * 32 + quad * 8];
                oacc[di] = __builtin_amdgcn_mfma_f32_16x16x32_bf16(a, bb, oacc[di], 0, 0, 0);
            }
        }
    }

#pragma unroll
    for (int r = 0; r < 4; ++r) {
        float inv = 1.f / lrow[r];
        size_t row = (size_t)(b * T + qt * 64 + wv * 16 + quad * 4 + r);
#pragma unroll
        for (int di = 0; di < 4; ++di)
            o[row * 1024 + h * 64 + di * 16 + lane15] = f2b(oacc[di][r] * inv);
    }
}

// ---------------------------------------------------------------------------
extern "C" void kernel_launch(void* const* d_in, const int* in_sizes, int n_in,
                              void* d_out, int out_size, void* d_ws, size_t ws_size,
                              hipStream_t stream)
{
    (void)in_sizes; (void)n_in; (void)out_size; (void)ws_size;
    const float* x   = (const float*)d_in[0];
    const float* Wq  = (const float*)d_in[1];
    const float* Wk  = (const float*)d_in[2];
    const float* Wv  = (const float*)d_in[3];
    const float* Wo  = (const float*)d_in[4];
    const float* bo  = (const float*)d_in[5];
    const float* g1  = (const float*)d_in[6];
    const float* be1 = (const float*)d_in[7];
    const float* g2  = (const float*)d_in[8];
    const float* be2 = (const float*)d_in[9];
    const float* W1  = (const float*)d_in[10];
    const float* b1  = (const float*)d_in[11];
    const float* W2  = (const float*)d_in[12];
    const float* b2  = (const float*)d_in[13];

    const int T = 2048, M = 4 * T;  // 8192 rows
    const size_t MB = 1ull << 20;
    char* ws = (char*)d_ws;

    // workspace map (128 MB total, with live-range overlays):
    bf16*  xn    = (bf16*)(ws + 0 * MB);     // 16 MB; later: attn out; later: hb
    bf16*  qkv   = (bf16*)(ws + 16 * MB);    // 48 MB [M][3072]; later: hb tail
    bf16*  vt    = (bf16*)(ws + 64 * MB);    // 16 MB [b][h][64][T]; later: x1
    bf16*  wqkvt = (bf16*)(ws + 80 * MB);    //  6 MB [3072][1024]; later: x1
    float* x1    = (float*)(ws + 64 * MB);   // 32 MB [M][1024] fp32
    bf16*  wot   = (bf16*)(ws + 96 * MB);    //  2 MB [1024][1024]; later: xn2
    bf16*  xn2   = (bf16*)(ws + 96 * MB);    // 16 MB
    bf16*  w1t   = (bf16*)(ws + 112 * MB);   //  8 MB [4096][1024]
    bf16*  w2t   = (bf16*)(ws + 120 * MB);   //  8 MB [1024][4096]
    bf16*  attnb = (bf16*)(ws + 0 * MB);
    bf16*  hb    = (bf16*)(ws + 0 * MB);     // 64 MB [M][4096]

    dim3 blk(256);

    // weight transposes -> bf16 B^T copies
    transpose_cvt<float><<<dim3(2, 32, 16), blk, 0, stream>>>(
        Wq, (long)1024 * 64, 64, wqkvt, (long)64 * 1024, 1024);
    transpose_cvt<float><<<dim3(2, 32, 16), blk, 0, stream>>>(
        Wk, (long)1024 * 64, 64, wqkvt + (size_t)1024 * 1024, (long)64 * 1024, 1024);
    transpose_cvt<float><<<dim3(2, 32, 16), blk, 0, stream>>>(
        Wv, (long)1024 * 64, 64, wqkvt + (size_t)2048 * 1024, (long)64 * 1024, 1024);
    transpose_cvt<float><<<dim3(32, 32, 1), blk, 0, stream>>>(Wo, 0, 1024, wot, 0, 1024);
    transpose_cvt<float><<<dim3(128, 32, 1), blk, 0, stream>>>(W1, 0, 4096, w1t, 0, 1024);
    transpose_cvt<float><<<dim3(32, 128, 1), blk, 0, stream>>>(W2, 0, 1024, w2t, 0, 4096);

    // LN1
    ln_kernel<<<M, blk, 0, stream>>>(x, g1, be1, xn);

    // fused QKV projection: [M,1024] @ [1024,3072]
    gemm_bt<false, false, false, float, bf16><<<dim3(24, 64), blk, 0, stream>>>(
        xn, 1024, wqkvt, 1024, nullptr, nullptr, 0, qkv, 3072, M, 3072, 1024);

    // V^T: vt[b][h][d][t] = qkv[(b*T+t)][2048 + h*64 + d]
    for (int b = 0; b < 4; ++b)
        transpose_cvt<bf16><<<dim3(2, 64, 16), blk, 0, stream>>>(
            qkv + (size_t)b * T * 3072 + 2048, 64, 3072,
            vt + (size_t)b * 16 * 64 * T, (long)64 * T, T);

    // causal flash attention
    attn_kernel<<<dim3(T / 64, 16, 4), blk, 0, stream>>>(qkv, vt, attnb, T);

    // x1 = x + attn @ Wo + bo
    gemm_bt<false, true, true, float, float><<<dim3(8, 64), blk, 0, stream>>>(
        attnb, 1024, wot, 1024, bo, x, 1024, x1, 1024, M, 1024, 1024);

    // LN2
    ln_kernel<<<M, blk, 0, stream>>>(x1, g2, be2, xn2);

    // h = relu(xn2 @ W1 + b1)
    gemm_bt<true, true, false, float, bf16><<<dim3(32, 64), blk, 0, stream>>>(
        xn2, 1024, w1t, 1024, b1, nullptr, 0, hb, 4096, M, 4096, 1024);

    // out = x1 + h @ W2 + b2
    gemm_bt<false, true, true, float, float><<<dim3(8, 64), blk, 0, stream>>>(
        hb, 4096, w2t, 4096, b2, x1, 1024, (float*)d_out, 1024, M, 1024, 4096);
}

// Round 4
// 661.617 us; speedup vs baseline: 10.5175x; 1.1807x over previous
//
#include <hip/hip_runtime.h>
#include <hip/hip_bf16.h>

typedef __hip_bfloat16 bf16;
typedef __attribute__((ext_vector_type(8))) short bf16x8;
typedef __attribute__((ext_vector_type(4))) short s16x4;
typedef __attribute__((ext_vector_type(4))) float f32x4;

__device__ __forceinline__ float b2f(bf16 v) { return __bfloat162float(v); }
__device__ __forceinline__ bf16  f2b(float v) { return __float2bfloat16(v); }
__device__ __forceinline__ float ldf(const bf16* p)  { return __bfloat162float(*p); }
__device__ __forceinline__ float ldf(const float* p) { return *p; }
__device__ __forceinline__ void  stf(bf16* p, float v)  { *p = __float2bfloat16(v); }
__device__ __forceinline__ void  stf(float* p, float v) { *p = v; }

// async global->LDS, 16 B per lane; LDS dest = wave-uniform base + lane*16
__device__ __forceinline__ void load_lds16(const bf16* g, short* lds) {
    __builtin_amdgcn_global_load_lds(
        (const __attribute__((address_space(1))) unsigned int*)g,
        (__attribute__((address_space(3))) unsigned int*)lds, 16, 0, 0);
}

// ---------------------------------------------------------------------------
// LayerNorm over last dim C=1024. One block (256 threads) per row. bf16 out.
// ---------------------------------------------------------------------------
__global__ __launch_bounds__(256) void ln_kernel(const float* __restrict__ x,
                                                 const float* __restrict__ g,
                                                 const float* __restrict__ b,
                                                 bf16* __restrict__ out)
{
    const int C = 1024;
    int row = blockIdx.x;
    int tid = threadIdx.x;
    const float* xr = x + (size_t)row * C;

    float v[4];
    float s = 0.f, s2 = 0.f;
#pragma unroll
    for (int i = 0; i < 4; ++i) {
        float f = xr[tid + i * 256];
        v[i] = f; s += f; s2 += f * f;
    }
#pragma unroll
    for (int off = 32; off > 0; off >>= 1) {
        s  += __shfl_down(s,  off, 64);
        s2 += __shfl_down(s2, off, 64);
    }
    __shared__ float red[8];
    int wave = tid >> 6;
    if ((tid & 63) == 0) { red[wave] = s; red[wave + 4] = s2; }
    __syncthreads();
    float ts  = red[0] + red[1] + red[2] + red[3];
    float ts2 = red[4] + red[5] + red[6] + red[7];
    float mu  = ts * (1.f / 1024.f);
    float var = ts2 * (1.f / 1024.f) - mu * mu;
    float rstd = rsqrtf(var + 1e-5f);
#pragma unroll
    for (int i = 0; i < 4; ++i) {
        int c = tid + i * 256;
        out[(size_t)row * C + c] = f2b((v[i] - mu) * rstd * g[c] + b[c]);
    }
}

// ---------------------------------------------------------------------------
// Tiled transpose + convert to bf16: out[n][k] = in[k][n].  32x32 LDS tiles.
// ---------------------------------------------------------------------------
template<typename InT>
__global__ __launch_bounds__(256) void transpose_cvt(
    const InT* __restrict__ in, long in_zoff, int in_ld,
    bf16* __restrict__ out, long out_zoff, int out_ld)
{
    __shared__ float t[32][33];
    int tx = threadIdx.x & 31, ty = threadIdx.x >> 5;  // 32 x 8
    const InT* ip = in + (size_t)blockIdx.z * in_zoff;
    bf16* op = out + (size_t)blockIdx.z * out_zoff;
    int n0 = blockIdx.x * 32, k0 = blockIdx.y * 32;
#pragma unroll
    for (int i = 0; i < 4; ++i)
        t[ty + i * 8][tx] = ldf(ip + (size_t)(k0 + ty + i * 8) * in_ld + n0 + tx);
    __syncthreads();
#pragma unroll
    for (int i = 0; i < 4; ++i)
        op[(size_t)(n0 + ty + i * 8) * out_ld + k0 + tx] = f2b(t[tx][ty + i * 8]);
}

// ---------------------------------------------------------------------------
// MFMA GEMM (m97 structure): C[M,N] = A[M,K] @ B[K,N], B given TRANSPOSED
// (Bt[n][k], ld=ldb). 128x128 tile, BK=32, 256 thr = 4 waves.
// ---------------------------------------------------------------------------
template<bool RELU, bool HAS_BIAS, bool HAS_RES, typename ResT, typename OutT>
__global__ __launch_bounds__(256) void gemm_bt(
    const bf16* __restrict__ A, int lda,
    const bf16* __restrict__ Bt, int ldb,
    const float* __restrict__ bias,
    const ResT* __restrict__ res, int ldr,
    OutT* __restrict__ Cm, int ldc,
    int M, int N, int K)
{
    __shared__ short As[128 * 32];
    __shared__ short Bs[128 * 32];
    int tid = threadIdx.x, wv = tid >> 6, ln = tid & 63;
    int bm0 = blockIdx.y * 128, bn0 = blockIdx.x * 128;
    int wm = (wv & 1) * 64, wn = (wv >> 1) * 64;
    int quad = ln >> 4, lane15 = ln & 15;

    f32x4 acc[4][4] = {};

    int srow = ln >> 2;
    int scol = (ln & 3) * 8;
    const bf16* Ab = A + (size_t)bm0 * lda;
    const bf16* Bb = Bt + (size_t)bn0 * ldb;

    for (int k0 = 0; k0 < K; k0 += 32) {
#pragma unroll
        for (int i = 0; i < 2; ++i) {
            int ch = wv + i * 4;
            load_lds16(Ab + (size_t)(ch * 16 + srow) * lda + k0 + scol, &As[ch * 16 * 32]);
            load_lds16(Bb + (size_t)(ch * 16 + srow) * ldb + k0 + scol, &Bs[ch * 16 * 32]);
        }
        __syncthreads();
        bf16x8 af[4], bfr[4];
#pragma unroll
        for (int mi = 0; mi < 4; ++mi)
            af[mi] = *(const bf16x8*)&As[(wm + mi * 16 + lane15) * 32 + quad * 8];
#pragma unroll
        for (int ni = 0; ni < 4; ++ni)
            bfr[ni] = *(const bf16x8*)&Bs[(wn + ni * 16 + lane15) * 32 + quad * 8];
#pragma unroll
        for (int mi = 0; mi < 4; ++mi)
#pragma unroll
            for (int ni = 0; ni < 4; ++ni)
                acc[mi][ni] = __builtin_amdgcn_mfma_f32_16x16x32_bf16(
                    af[mi], bfr[ni], acc[mi][ni], 0, 0, 0);
        __syncthreads();
    }

#pragma unroll
    for (int mi = 0; mi < 4; ++mi) {
#pragma unroll
        for (int r = 0; r < 4; ++r) {
            int gm = bm0 + wm + mi * 16 + quad * 4 + r;
#pragma unroll
            for (int ni = 0; ni < 4; ++ni) {
                int gn = bn0 + wn + ni * 16 + lane15;
                float v = acc[mi][ni][r];
                if (HAS_BIAS) v += bias[gn];
                if (HAS_RES)  v += ldf(res + (size_t)gm * ldr + gn);
                if (RELU)     v = fmaxf(v, 0.f);
                stf(Cm + (size_t)gm * ldc + gn, v);
            }
        }
    }
}

// ---------------------------------------------------------------------------
// MFMA causal flash attention, S^T formulation. Grid (T/64, H, B), 4 waves.
// qkv: [M][3072] bf16. vt: [b][h][64 d][T] bf16.
// Wave handles 16 q-rows x 64 keys per tile. S^T = K.Q^T so C/D col(lane15)
// = q-row: softmax is in-lane (16 keys/lane) + 2 cross-quad shuffles for the
// row max. O^T = V^T.P^T accumulated in C-layout (d=quad*4+r, q=lane15).
// ---------------------------------------------------------------------------
__global__ __launch_bounds__(256) void attn_kernel(
    const bf16* __restrict__ qkv, const bf16* __restrict__ vt,
    bf16* __restrict__ o, int T)
{
    const int LDQ = 3072;
    const int PS = 72;   // Ps row stride (shorts): 144 B, 16B-aligned, bank-spread
    int qt = blockIdx.x, h = blockIdx.y, b = blockIdx.z;
    int tid = threadIdx.x, wv = tid >> 6, ln = tid & 63;
    int quad = ln >> 4, lane15 = ln & 15;

    __shared__ short Qs[64 * 64];     // [qrow][d]
    __shared__ short Ks[64 * 64];     // [key][d]
    __shared__ short Vs[64 * 64];     // [d][key]
    __shared__ short Ps[4][16 * PS];  // per-wave [qrow16][key64]

    int lr = ln >> 3, lc = (ln & 7) * 8;

#pragma unroll
    for (int i = 0; i < 2; ++i) {
        int ch = wv * 2 + i;
        load_lds16(qkv + (size_t)(b * T + qt * 64 + ch * 8 + lr) * LDQ + h * 64 + lc,
                   &Qs[ch * 8 * 64]);
    }

    f32x4 oacc[4] = {};
    float mrun = -1e30f, lrun = 0.f;
    const float scale = 0.125f;  // 1/sqrt(64)

    const bf16* kbase = qkv + (size_t)(b * T) * LDQ + 1024 + h * 64;
    const bf16* vbase = vt + (size_t)((b * 16 + h) * 64) * T;

    for (int kt = 0; kt <= qt; ++kt) {
        __syncthreads();   // prev-iter LDS reads done (and Q staging drain at kt=0)
#pragma unroll
        for (int i = 0; i < 2; ++i) {
            int ch = wv * 2 + i;
            load_lds16(kbase + (size_t)(kt * 64 + ch * 8 + lr) * LDQ + lc, &Ks[ch * 8 * 64]);
            load_lds16(vbase + (size_t)(ch * 8 + lr) * T + kt * 64 + lc, &Vs[ch * 8 * 64]);
        }
        __syncthreads();

        // S^T = K Q^T : sacc[mi] holds S^T[key = mi*16+quad*4+r][q = lane15]
        f32x4 sacc[4] = {};
#pragma unroll
        for (int ks = 0; ks < 2; ++ks) {
            bf16x8 qf = *(const bf16x8*)&Qs[(wv * 16 + lane15) * 64 + ks * 32 + quad * 8];
#pragma unroll
            for (int mi = 0; mi < 4; ++mi) {
                bf16x8 kf = *(const bf16x8*)&Ks[(mi * 16 + lane15) * 64 + ks * 32 + quad * 8];
                sacc[mi] = __builtin_amdgcn_mfma_f32_16x16x32_bf16(kf, qf, sacc[mi], 0, 0, 0);
            }
        }

        // causal mask: only the diagonal tile needs it
        if (kt == qt) {
            int ql = wv * 16 + lane15;
#pragma unroll
            for (int mi = 0; mi < 4; ++mi)
#pragma unroll
                for (int r = 0; r < 4; ++r)
                    if (mi * 16 + quad * 4 + r > ql) sacc[mi][r] = -3e38f;
        }

        // in-lane row max over this lane's 16 keys, then cross-quad reduce
        float mx = sacc[0][0];
#pragma unroll
        for (int mi = 0; mi < 4; ++mi)
#pragma unroll
            for (int r = 0; r < 4; ++r) mx = fmaxf(mx, sacc[mi][r]);
        mx = fmaxf(mx, __shfl_xor(mx, 16, 64));
        mx = fmaxf(mx, __shfl_xor(mx, 32, 64));
        float mn = fmaxf(mrun, mx * scale);
        float alpha = __expf(mrun - mn);
        mrun = mn;

        float psum = 0.f;
#pragma unroll
        for (int mi = 0; mi < 4; ++mi) {
            float p[4];
#pragma unroll
            for (int r = 0; r < 4; ++r) {
                p[r] = __expf(fmaf(sacc[mi][r], scale, -mn));
                psum += p[r];
            }
            short tmp[4];
#pragma unroll
            for (int r = 0; r < 4; ++r) {
                bf16 pb = f2b(p[r]);
                tmp[r] = *(short*)&pb;
            }
            *(s16x4*)&Ps[wv][lane15 * PS + mi * 16 + quad * 4] = *(s16x4*)tmp;
        }
        lrun = lrun * alpha + psum;
#pragma unroll
        for (int di = 0; di < 4; ++di)
#pragma unroll
            for (int r = 0; r < 4; ++r) oacc[di][r] *= alpha;

        // O^T += V^T P^T  (wave-private Ps: no barrier needed)
#pragma unroll
        for (int ks = 0; ks < 2; ++ks) {
            bf16x8 pf = *(const bf16x8*)&Ps[wv][lane15 * PS + ks * 32 + quad * 8];
#pragma unroll
            for (int di = 0; di < 4; ++di) {
                bf16x8 vf = *(const bf16x8*)&Vs[(di * 16 + lane15) * 64 + ks * 32 + quad * 8];
                oacc[di] = __builtin_amdgcn_mfma_f32_16x16x32_bf16(vf, pf, oacc[di], 0, 0, 0);
            }
        }
    }

    // full row l: sum partials across the 4 quads
    lrun += __shfl_xor(lrun, 16, 64);
    lrun += __shfl_xor(lrun, 32, 64);
    float inv = 1.f / lrun;

    size_t row = (size_t)(b * T + qt * 64 + wv * 16 + lane15);
#pragma unroll
    for (int di = 0; di < 4; ++di) {
        short tmp[4];
#pragma unroll
        for (int r = 0; r < 4; ++r) {
            bf16 ob = f2b(oacc[di][r] * inv);
            tmp[r] = *(short*)&ob;
        }
        *(s16x4*)&o[row * 1024 + h * 64 + di * 16 + quad * 4] = *(s16x4*)tmp;
    }
}

// ---------------------------------------------------------------------------
extern "C" void kernel_launch(void* const* d_in, const int* in_sizes, int n_in,
                              void* d_out, int out_size, void* d_ws, size_t ws_size,
                              hipStream_t stream)
{
    (void)in_sizes; (void)n_in; (void)out_size; (void)ws_size;
    const float* x   = (const float*)d_in[0];
    const float* Wq  = (const float*)d_in[1];
    const float* Wk  = (const float*)d_in[2];
    const float* Wv  = (const float*)d_in[3];
    const float* Wo  = (const float*)d_in[4];
    const float* bo  = (const float*)d_in[5];
    const float* g1  = (const float*)d_in[6];
    const float* be1 = (const float*)d_in[7];
    const float* g2  = (const float*)d_in[8];
    const float* be2 = (const float*)d_in[9];
    const float* W1  = (const float*)d_in[10];
    const float* b1  = (const float*)d_in[11];
    const float* W2  = (const float*)d_in[12];
    const float* b2  = (const float*)d_in[13];

    const int T = 2048, M = 4 * T;  // 8192 rows
    const size_t MB = 1ull << 20;
    char* ws = (char*)d_ws;

    bf16*  xn    = (bf16*)(ws + 0 * MB);     // 16 MB; later: attn out; later: hb
    bf16*  qkv   = (bf16*)(ws + 16 * MB);    // 48 MB [M][3072]
    bf16*  vt    = (bf16*)(ws + 64 * MB);    // 16 MB [b][h][64][T]; later: x1
    bf16*  wqkvt = (bf16*)(ws + 80 * MB);    //  6 MB [3072][1024]; later: x1
    float* x1    = (float*)(ws + 64 * MB);   // 32 MB [M][1024] fp32
    bf16*  wot   = (bf16*)(ws + 96 * MB);    //  2 MB; later: xn2
    bf16*  xn2   = (bf16*)(ws + 96 * MB);    // 16 MB
    bf16*  w1t   = (bf16*)(ws + 112 * MB);   //  8 MB [4096][1024]
    bf16*  w2t   = (bf16*)(ws + 120 * MB);   //  8 MB [1024][4096]
    bf16*  attnb = (bf16*)(ws + 0 * MB);
    bf16*  hb    = (bf16*)(ws + 0 * MB);     // 64 MB [M][4096]

    dim3 blk(256);

    transpose_cvt<float><<<dim3(2, 32, 16), blk, 0, stream>>>(
        Wq, (long)1024 * 64, 64, wqkvt, (long)64 * 1024, 1024);
    transpose_cvt<float><<<dim3(2, 32, 16), blk, 0, stream>>>(
        Wk, (long)1024 * 64, 64, wqkvt + (size_t)1024 * 1024, (long)64 * 1024, 1024);
    transpose_cvt<float><<<dim3(2, 32, 16), blk, 0, stream>>>(
        Wv, (long)1024 * 64, 64, wqkvt + (size_t)2048 * 1024, (long)64 * 1024, 1024);
    transpose_cvt<float><<<dim3(32, 32, 1), blk, 0, stream>>>(Wo, 0, 1024, wot, 0, 1024);
    transpose_cvt<float><<<dim3(128, 32, 1), blk, 0, stream>>>(W1, 0, 4096, w1t, 0, 1024);
    transpose_cvt<float><<<dim3(32, 128, 1), blk, 0, stream>>>(W2, 0, 1024, w2t, 0, 4096);

    ln_kernel<<<M, blk, 0, stream>>>(x, g1, be1, xn);

    gemm_bt<false, false, false, float, bf16><<<dim3(24, 64), blk, 0, stream>>>(
        xn, 1024, wqkvt, 1024, nullptr, nullptr, 0, qkv, 3072, M, 3072, 1024);

    for (int b = 0; b < 4; ++b)
        transpose_cvt<bf16><<<dim3(2, 64, 16), blk, 0, stream>>>(
            qkv + (size_t)b * T * 3072 + 2048, 64, 3072,
            vt + (size_t)b * 16 * 64 * T, (long)64 * T, T);

    attn_kernel<<<dim3(T / 64, 16, 4), blk, 0, stream>>>(qkv, vt, attnb, T);

    gemm_bt<false, true, true, float, float><<<dim3(8, 64), blk, 0, stream>>>(
        attnb, 1024, wot, 1024, bo, x, 1024, x1, 1024, M, 1024, 1024);

    ln_kernel<<<M, blk, 0, stream>>>(x1, g2, be2, xn2);

    gemm_bt<true, true, false, float, bf16><<<dim3(32, 64), blk, 0, stream>>>(
        xn2, 1024, w1t, 1024, b1, nullptr, 0, hb, 4096, M, 4096, 1024);

    gemm_bt<false, true, true, float, float><<<dim3(8, 64), blk, 0, stream>>>(
        hb, 4096, w2t, 4096, b2, x1, 1024, (float*)d_out, 1024, M, 1024, 4096);
}

// Round 5
// 650.001 us; speedup vs baseline: 10.7054x; 1.0179x over previous
//
#include <hip/hip_runtime.h>
#include <hip/hip_bf16.h>

typedef __hip_bfloat16 bf16;
typedef __attribute__((ext_vector_type(8))) short bf16x8;
typedef __attribute__((ext_vector_type(4))) short s16x4;
typedef __attribute__((ext_vector_type(4))) float f32x4;

__device__ __forceinline__ float b2f(bf16 v) { return __bfloat162float(v); }
__device__ __forceinline__ bf16  f2b(float v) { return __float2bfloat16(v); }
__device__ __forceinline__ float ldf(const bf16* p)  { return __bfloat162float(*p); }
__device__ __forceinline__ float ldf(const float* p) { return *p; }
__device__ __forceinline__ void  stf(bf16* p, float v)  { *p = __float2bfloat16(v); }
__device__ __forceinline__ void  stf(float* p, float v) { *p = v; }

// async global->LDS, 16 B per lane; LDS dest = wave-uniform base + lane*16
__device__ __forceinline__ void load_lds16(const bf16* g, short* lds) {
    __builtin_amdgcn_global_load_lds(
        (const __attribute__((address_space(1))) unsigned int*)g,
        (__attribute__((address_space(3))) unsigned int*)lds, 16, 0, 0);
}

// ---------------------------------------------------------------------------
// LayerNorm over last dim C=1024. One block (256 threads) per row. bf16 out.
// ---------------------------------------------------------------------------
template<typename InT>
__global__ __launch_bounds__(256) void ln_kernel(const InT* __restrict__ x,
                                                 const float* __restrict__ g,
                                                 const float* __restrict__ b,
                                                 bf16* __restrict__ out)
{
    const int C = 1024;
    int row = blockIdx.x;
    int tid = threadIdx.x;
    const InT* xr = x + (size_t)row * C;

    float v[4];
    float s = 0.f, s2 = 0.f;
#pragma unroll
    for (int i = 0; i < 4; ++i) {
        float f = ldf(xr + tid + i * 256);
        v[i] = f; s += f; s2 += f * f;
    }
#pragma unroll
    for (int off = 32; off > 0; off >>= 1) {
        s  += __shfl_down(s,  off, 64);
        s2 += __shfl_down(s2, off, 64);
    }
    __shared__ float red[8];
    int wave = tid >> 6;
    if ((tid & 63) == 0) { red[wave] = s; red[wave + 4] = s2; }
    __syncthreads();
    float ts  = red[0] + red[1] + red[2] + red[3];
    float ts2 = red[4] + red[5] + red[6] + red[7];
    float mu  = ts * (1.f / 1024.f);
    float var = ts2 * (1.f / 1024.f) - mu * mu;
    float rstd = rsqrtf(var + 1e-5f);
#pragma unroll
    for (int i = 0; i < 4; ++i) {
        int c = tid + i * 256;
        out[(size_t)row * C + c] = f2b((v[i] - mu) * rstd * g[c] + b[c]);
    }
}

// ---------------------------------------------------------------------------
// All six weight transposes (fp32 -> bf16, out[n][k] = in[k][n]) in ONE
// kernel. Flat tile id selects matrix + 32x32 tile.
//   [0,3072):   Wq/Wk/Wv  per-head [1024][64] -> wqkvt rows (m*1024+z*64..)
//   [3072,4096): Wo  [1024][1024] -> wot
//   [4096,8192): W1  [1024][4096] -> w1t [4096][1024]
//   [8192,12288): W2 [4096][1024] -> w2t [1024][4096]
// ---------------------------------------------------------------------------
__global__ __launch_bounds__(256) void prep_weights(
    const float* __restrict__ Wq, const float* __restrict__ Wk,
    const float* __restrict__ Wv, const float* __restrict__ Wo,
    const float* __restrict__ W1, const float* __restrict__ W2,
    bf16* __restrict__ wqkvt, bf16* __restrict__ wot,
    bf16* __restrict__ w1t, bf16* __restrict__ w2t)
{
    __shared__ float t[32][33];
    int tx = threadIdx.x & 31, ty = threadIdx.x >> 5;
    int id = blockIdx.x;
    const float* in; bf16* out; int in_ld, out_ld, n0, k0;
    if (id < 3072) {
        const float* Ws[3] = {Wq, Wk, Wv};
        int m = id >> 10, r = id & 1023;
        int z = r >> 6, rt = r & 63;
        in = Ws[m] + z * 65536;                       // [1024][64]
        out = wqkvt + (size_t)(m * 1024 + z * 64) * 1024;
        in_ld = 64; out_ld = 1024;
        n0 = (rt & 1) * 32; k0 = (rt >> 1) * 32;
    } else if (id < 4096) {
        int r = id - 3072;
        in = Wo; out = wot; in_ld = 1024; out_ld = 1024;
        n0 = (r & 31) * 32; k0 = (r >> 5) * 32;
    } else if (id < 8192) {
        int r = id - 4096;
        in = W1; out = w1t; in_ld = 4096; out_ld = 1024;
        n0 = (r & 127) * 32; k0 = (r >> 7) * 32;
    } else {
        int r = id - 8192;
        in = W2; out = w2t; in_ld = 1024; out_ld = 4096;
        n0 = (r & 31) * 32; k0 = (r >> 5) * 32;
    }
#pragma unroll
    for (int i = 0; i < 4; ++i)
        t[ty + i * 8][tx] = in[(size_t)(k0 + ty + i * 8) * in_ld + n0 + tx];
    __syncthreads();
#pragma unroll
    for (int i = 0; i < 4; ++i)
        out[(size_t)(n0 + ty + i * 8) * out_ld + k0 + tx] = f2b(t[tx][ty + i * 8]);
}

// ---------------------------------------------------------------------------
// V^T: vt[(b*16+h)*64 + d][t] = qkv[(b*T+t)*3072 + 2048 + h*64 + d]
// grid (2, T/32, 64) — z = b*16+h.
// ---------------------------------------------------------------------------
__global__ __launch_bounds__(256) void vt_kernel(
    const bf16* __restrict__ qkv, bf16* __restrict__ vt, int T)
{
    __shared__ float t[32][33];
    int tx = threadIdx.x & 31, ty = threadIdx.x >> 5;
    int z = blockIdx.z, b = z >> 4, h = z & 15;
    const bf16* in = qkv + (size_t)b * T * 3072 + 2048 + h * 64;  // [t][d] ld 3072
    bf16* out = vt + (size_t)z * 64 * T;                          // [d][t] ld T
    int n0 = blockIdx.x * 32, k0 = blockIdx.y * 32;
#pragma unroll
    for (int i = 0; i < 4; ++i)
        t[ty + i * 8][tx] = b2f(in[(size_t)(k0 + ty + i * 8) * 3072 + n0 + tx]);
    __syncthreads();
#pragma unroll
    for (int i = 0; i < 4; ++i)
        out[(size_t)(n0 + ty + i * 8) * T + k0 + tx] = f2b(t[tx][ty + i * 8]);
}

// ---------------------------------------------------------------------------
// MFMA GEMM (m97 structure): C[M,N] = A[M,K] @ B[K,N], B given TRANSPOSED
// (Bt[n][k], ld=ldb). 128x128 tile, BK=32, 256 thr = 4 waves.
// ---------------------------------------------------------------------------
template<bool RELU, bool HAS_BIAS, bool HAS_RES, typename ResT, typename OutT>
__global__ __launch_bounds__(256) void gemm_bt(
    const bf16* __restrict__ A, int lda,
    const bf16* __restrict__ Bt, int ldb,
    const float* __restrict__ bias,
    const ResT* __restrict__ res, int ldr,
    OutT* __restrict__ Cm, int ldc,
    int M, int N, int K)
{
    __shared__ short As[128 * 32];
    __shared__ short Bs[128 * 32];
    int tid = threadIdx.x, wv = tid >> 6, ln = tid & 63;
    int bm0 = blockIdx.y * 128, bn0 = blockIdx.x * 128;
    int wm = (wv & 1) * 64, wn = (wv >> 1) * 64;
    int quad = ln >> 4, lane15 = ln & 15;

    f32x4 acc[4][4] = {};

    int srow = ln >> 2;
    int scol = (ln & 3) * 8;
    const bf16* Ab = A + (size_t)bm0 * lda;
    const bf16* Bb = Bt + (size_t)bn0 * ldb;

    for (int k0 = 0; k0 < K; k0 += 32) {
#pragma unroll
        for (int i = 0; i < 2; ++i) {
            int ch = wv + i * 4;
            load_lds16(Ab + (size_t)(ch * 16 + srow) * lda + k0 + scol, &As[ch * 16 * 32]);
            load_lds16(Bb + (size_t)(ch * 16 + srow) * ldb + k0 + scol, &Bs[ch * 16 * 32]);
        }
        __syncthreads();
        bf16x8 af[4], bfr[4];
#pragma unroll
        for (int mi = 0; mi < 4; ++mi)
            af[mi] = *(const bf16x8*)&As[(wm + mi * 16 + lane15) * 32 + quad * 8];
#pragma unroll
        for (int ni = 0; ni < 4; ++ni)
            bfr[ni] = *(const bf16x8*)&Bs[(wn + ni * 16 + lane15) * 32 + quad * 8];
#pragma unroll
        for (int mi = 0; mi < 4; ++mi)
#pragma unroll
            for (int ni = 0; ni < 4; ++ni)
                acc[mi][ni] = __builtin_amdgcn_mfma_f32_16x16x32_bf16(
                    af[mi], bfr[ni], acc[mi][ni], 0, 0, 0);
        __syncthreads();
    }

#pragma unroll
    for (int mi = 0; mi < 4; ++mi) {
#pragma unroll
        for (int r = 0; r < 4; ++r) {
            int gm = bm0 + wm + mi * 16 + quad * 4 + r;
#pragma unroll
            for (int ni = 0; ni < 4; ++ni) {
                int gn = bn0 + wn + ni * 16 + lane15;
                float v = acc[mi][ni][r];
                if (HAS_BIAS) v += bias[gn];
                if (HAS_RES)  v += ldf(res + (size_t)gm * ldr + gn);
                if (RELU)     v = fmaxf(v, 0.f);
                stf(Cm + (size_t)gm * ldc + gn, v);
            }
        }
    }
}

// ---------------------------------------------------------------------------
// MFMA causal flash attention, S^T formulation, 128-row q-tile.
// Grid (T/128, H, B), 512 thr = 8 waves; wave wv owns q-rows wv*16..+15.
// Per 64-key tile: stage K/V (1 load_lds16 per wave per buffer), S^T = K.Q^T,
// in-lane softmax (16 keys/lane, q-row = lane15), O^T += V^T.P^T.
// Fully-masked wave-tiles skip compute (barrier counts stay uniform).
// ---------------------------------------------------------------------------
__global__ __launch_bounds__(512) void attn_kernel(
    const bf16* __restrict__ qkv, const bf16* __restrict__ vt,
    bf16* __restrict__ o, int T)
{
    const int LDQ = 3072;
    const int PS = 72;   // Ps row stride (shorts): 144 B, 16B-aligned, bank-spread
    int qt = blockIdx.x, h = blockIdx.y, b = blockIdx.z;
    int tid = threadIdx.x, wv = tid >> 6, ln = tid & 63;
    int quad = ln >> 4, lane15 = ln & 15;

    __shared__ short Qs[128 * 64];    // [qrow][d]
    __shared__ short Ks[64 * 64];     // [key][d]
    __shared__ short Vs[64 * 64];     // [d][key]
    __shared__ short Ps[8][16 * PS];  // per-wave [qrow16][key64]

    int lr = ln >> 3, lc = (ln & 7) * 8;

    // Q staging: wave wv loads rows [wv*16, wv*16+16)
#pragma unroll
    for (int i = 0; i < 2; ++i) {
        int ch = wv * 2 + i;
        load_lds16(qkv + (size_t)(b * T + qt * 128 + ch * 8 + lr) * LDQ + h * 64 + lc,
                   &Qs[ch * 8 * 64]);
    }

    f32x4 oacc[4] = {};
    float mrun = -1e30f, lrun = 0.f;
    const float scale = 0.125f;  // 1/sqrt(64)

    const bf16* kbase = qkv + (size_t)(b * T) * LDQ + 1024 + h * 64;
    const bf16* vbase = vt + (size_t)((b * 16 + h) * 64) * T;

    int qmin = qt * 128 + wv * 16;   // wave's first q-row
    int ntiles = 2 * qt + 2;

    for (int kt = 0; kt < ntiles; ++kt) {
        __syncthreads();   // prev-iter LDS reads done (and Q staging drain at kt=0)
        load_lds16(kbase + (size_t)(kt * 64 + wv * 8 + lr) * LDQ + lc, &Ks[wv * 8 * 64]);
        load_lds16(vbase + (size_t)(wv * 8 + lr) * T + kt * 64 + lc, &Vs[wv * 8 * 64]);
        __syncthreads();

        if (kt * 64 > qmin + 15) continue;   // fully masked for this wave

        // S^T = K Q^T : sacc[mi] holds S^T[key = mi*16+quad*4+r][q = lane15]
        f32x4 sacc[4] = {};
#pragma unroll
        for (int ks = 0; ks < 2; ++ks) {
            bf16x8 qf = *(const bf16x8*)&Qs[(wv * 16 + lane15) * 64 + ks * 32 + quad * 8];
#pragma unroll
            for (int mi = 0; mi < 4; ++mi) {
                bf16x8 kf = *(const bf16x8*)&Ks[(mi * 16 + lane15) * 64 + ks * 32 + quad * 8];
                sacc[mi] = __builtin_amdgcn_mfma_f32_16x16x32_bf16(kf, qf, sacc[mi], 0, 0, 0);
            }
        }

        // causal mask: only tiles containing this wave's diagonal
        if (kt * 64 + 63 > qmin) {
            int ql = qmin + lane15;
#pragma unroll
            for (int mi = 0; mi < 4; ++mi)
#pragma unroll
                for (int r = 0; r < 4; ++r)
                    if (kt * 64 + mi * 16 + quad * 4 + r > ql) sacc[mi][r] = -3e38f;
        }

        // in-lane row max over this lane's 16 keys, then cross-quad reduce
        float mx = sacc[0][0];
#pragma unroll
        for (int mi = 0; mi < 4; ++mi)
#pragma unroll
            for (int r = 0; r < 4; ++r) mx = fmaxf(mx, sacc[mi][r]);
        mx = fmaxf(mx, __shfl_xor(mx, 16, 64));
        mx = fmaxf(mx, __shfl_xor(mx, 32, 64));
        float mn = fmaxf(mrun, mx * scale);
        float alpha = __expf(mrun - mn);
        mrun = mn;

        float psum = 0.f;
#pragma unroll
        for (int mi = 0; mi < 4; ++mi) {
            float p[4];
#pragma unroll
            for (int r = 0; r < 4; ++r) {
                p[r] = __expf(fmaf(sacc[mi][r], scale, -mn));
                psum += p[r];
            }
            short tmp[4];
#pragma unroll
            for (int r = 0; r < 4; ++r) {
                bf16 pb = f2b(p[r]);
                tmp[r] = *(short*)&pb;
            }
            *(s16x4*)&Ps[wv][lane15 * PS + mi * 16 + quad * 4] = *(s16x4*)tmp;
        }
        lrun = lrun * alpha + psum;
#pragma unroll
        for (int di = 0; di < 4; ++di)
#pragma unroll
            for (int r = 0; r < 4; ++r) oacc[di][r] *= alpha;

        // O^T += V^T P^T  (wave-private Ps: no barrier needed)
#pragma unroll
        for (int ks = 0; ks < 2; ++ks) {
            bf16x8 pf = *(const bf16x8*)&Ps[wv][lane15 * PS + ks * 32 + quad * 8];
#pragma unroll
            for (int di = 0; di < 4; ++di) {
                bf16x8 vf = *(const bf16x8*)&Vs[(di * 16 + lane15) * 64 + ks * 32 + quad * 8];
                oacc[di] = __builtin_amdgcn_mfma_f32_16x16x32_bf16(vf, pf, oacc[di], 0, 0, 0);
            }
        }
    }

    // full row l: sum partials across the 4 quads
    lrun += __shfl_xor(lrun, 16, 64);
    lrun += __shfl_xor(lrun, 32, 64);
    float inv = 1.f / lrun;

    size_t row = (size_t)(b * T + qt * 128 + wv * 16 + lane15);
#pragma unroll
    for (int di = 0; di < 4; ++di) {
        short tmp[4];
#pragma unroll
        for (int r = 0; r < 4; ++r) {
            bf16 ob = f2b(oacc[di][r] * inv);
            tmp[r] = *(short*)&ob;
        }
        *(s16x4*)&o[row * 1024 + h * 64 + di * 16 + quad * 4] = *(s16x4*)tmp;
    }
}

// ---------------------------------------------------------------------------
extern "C" void kernel_launch(void* const* d_in, const int* in_sizes, int n_in,
                              void* d_out, int out_size, void* d_ws, size_t ws_size,
                              hipStream_t stream)
{
    (void)in_sizes; (void)n_in; (void)out_size; (void)ws_size;
    const float* x   = (const float*)d_in[0];
    const float* Wq  = (const float*)d_in[1];
    const float* Wk  = (const float*)d_in[2];
    const float* Wv  = (const float*)d_in[3];
    const float* Wo  = (const float*)d_in[4];
    const float* bo  = (const float*)d_in[5];
    const float* g1  = (const float*)d_in[6];
    const float* be1 = (const float*)d_in[7];
    const float* g2  = (const float*)d_in[8];
    const float* be2 = (const float*)d_in[9];
    const float* W1  = (const float*)d_in[10];
    const float* b1  = (const float*)d_in[11];
    const float* W2  = (const float*)d_in[12];
    const float* b2  = (const float*)d_in[13];

    const int T = 2048, M = 4 * T;  // 8192 rows
    const size_t MB = 1ull << 20;
    char* ws = (char*)d_ws;

    // workspace map (128 MB, live-range overlays):
    bf16*  xn    = (bf16*)(ws + 0 * MB);     // 16 MB; later: attnb; later: hb
    bf16*  qkv   = (bf16*)(ws + 16 * MB);    // 48 MB [M][3072]; later: hb tail
    bf16*  vt    = (bf16*)(ws + 64 * MB);    // 16 MB [b*16+h][64][T]
    bf16*  wqkvt = (bf16*)(ws + 80 * MB);    //  6 MB [3072][1024]; later: x1b
    bf16*  x1b   = (bf16*)(ws + 80 * MB);    // 16 MB [M][1024] bf16 residual
    bf16*  wot   = (bf16*)(ws + 96 * MB);    //  2 MB; later: xn2
    bf16*  xn2   = (bf16*)(ws + 96 * MB);    // 16 MB
    bf16*  w1t   = (bf16*)(ws + 112 * MB);   //  8 MB [4096][1024]
    bf16*  w2t   = (bf16*)(ws + 120 * MB);   //  8 MB [1024][4096]
    bf16*  attnb = (bf16*)(ws + 0 * MB);
    bf16*  hb    = (bf16*)(ws + 0 * MB);     // 64 MB [M][4096]

    dim3 blk(256);

    // all weight transposes in one launch
    prep_weights<<<12288, blk, 0, stream>>>(Wq, Wk, Wv, Wo, W1, W2,
                                            wqkvt, wot, w1t, w2t);

    // LN1
    ln_kernel<float><<<M, blk, 0, stream>>>(x, g1, be1, xn);

    // fused QKV projection: [M,1024] @ [1024,3072]
    gemm_bt<false, false, false, float, bf16><<<dim3(24, 64), blk, 0, stream>>>(
        xn, 1024, wqkvt, 1024, nullptr, nullptr, 0, qkv, 3072, M, 3072, 1024);

    // V^T
    vt_kernel<<<dim3(2, T / 32, 64), blk, 0, stream>>>(qkv, vt, T);

    // causal flash attention (128-row q-tiles, 512 threads)
    attn_kernel<<<dim3(T / 128, 16, 4), dim3(512), 0, stream>>>(qkv, vt, attnb, T);

    // x1 = x + attn @ Wo + bo   (bf16 out)
    gemm_bt<false, true, true, float, bf16><<<dim3(8, 64), blk, 0, stream>>>(
        attnb, 1024, wot, 1024, bo, x, 1024, x1b, 1024, M, 1024, 1024);

    // LN2 (bf16 in)
    ln_kernel<bf16><<<M, blk, 0, stream>>>(x1b, g2, be2, xn2);

    // h = relu(xn2 @ W1 + b1)
    gemm_bt<true, true, false, float, bf16><<<dim3(32, 64), blk, 0, stream>>>(
        xn2, 1024, w1t, 1024, b1, nullptr, 0, hb, 4096, M, 4096, 1024);

    // out = x1 + h @ W2 + b2   (fp32 out, bf16 residual)
    gemm_bt<false, true, true, bf16, float><<<dim3(8, 64), blk, 0, stream>>>(
        hb, 4096, w2t, 4096, b2, x1b, 1024, (float*)d_out, 1024, M, 1024, 4096);
}

// Round 6
// 586.270 us; speedup vs baseline: 11.8692x; 1.1087x over previous
//
#include <hip/hip_runtime.h>
#include <hip/hip_bf16.h>

typedef __hip_bfloat16 bf16;
typedef __attribute__((ext_vector_type(8))) short bf16x8;
typedef __attribute__((ext_vector_type(4))) short s16x4;
typedef __attribute__((ext_vector_type(4))) float f32x4;

__device__ __forceinline__ float b2f(bf16 v) { return __bfloat162float(v); }
__device__ __forceinline__ bf16  f2b(float v) { return __float2bfloat16(v); }
__device__ __forceinline__ float ldf(const bf16* p)  { return __bfloat162float(*p); }
__device__ __forceinline__ float ldf(const float* p) { return *p; }
__device__ __forceinline__ void  stf(bf16* p, float v)  { *p = __float2bfloat16(v); }
__device__ __forceinline__ void  stf(float* p, float v) { *p = v; }

// async global->LDS, 16 B per lane; LDS dest = wave-uniform base + lane*16
__device__ __forceinline__ void load_lds16(const bf16* g, short* lds) {
    __builtin_amdgcn_global_load_lds(
        (const __attribute__((address_space(1))) unsigned int*)g,
        (__attribute__((address_space(3))) unsigned int*)lds, 16, 0, 0);
}

// ---------------------------------------------------------------------------
// LayerNorm over last dim C=1024. One block (256 threads) per row. bf16 out.
// ---------------------------------------------------------------------------
template<typename InT>
__global__ __launch_bounds__(256) void ln_kernel(const InT* __restrict__ x,
                                                 const float* __restrict__ g,
                                                 const float* __restrict__ b,
                                                 bf16* __restrict__ out)
{
    const int C = 1024;
    int row = blockIdx.x;
    int tid = threadIdx.x;
    const InT* xr = x + (size_t)row * C;

    float v[4];
    float s = 0.f, s2 = 0.f;
#pragma unroll
    for (int i = 0; i < 4; ++i) {
        float f = ldf(xr + tid + i * 256);
        v[i] = f; s += f; s2 += f * f;
    }
#pragma unroll
    for (int off = 32; off > 0; off >>= 1) {
        s  += __shfl_down(s,  off, 64);
        s2 += __shfl_down(s2, off, 64);
    }
    __shared__ float red[8];
    int wave = tid >> 6;
    if ((tid & 63) == 0) { red[wave] = s; red[wave + 4] = s2; }
    __syncthreads();
    float ts  = red[0] + red[1] + red[2] + red[3];
    float ts2 = red[4] + red[5] + red[6] + red[7];
    float mu  = ts * (1.f / 1024.f);
    float var = ts2 * (1.f / 1024.f) - mu * mu;
    float rstd = rsqrtf(var + 1e-5f);
#pragma unroll
    for (int i = 0; i < 4; ++i) {
        int c = tid + i * 256;
        out[(size_t)row * C + c] = f2b((v[i] - mu) * rstd * g[c] + b[c]);
    }
}

// ---------------------------------------------------------------------------
// All six weight transposes (fp32 -> bf16, out[n][k] = in[k][n]) in ONE
// kernel. Flat tile id selects matrix + 32x32 tile.
// ---------------------------------------------------------------------------
__global__ __launch_bounds__(256) void prep_weights(
    const float* __restrict__ Wq, const float* __restrict__ Wk,
    const float* __restrict__ Wv, const float* __restrict__ Wo,
    const float* __restrict__ W1, const float* __restrict__ W2,
    bf16* __restrict__ wqkvt, bf16* __restrict__ wot,
    bf16* __restrict__ w1t, bf16* __restrict__ w2t)
{
    __shared__ float t[32][33];
    int tx = threadIdx.x & 31, ty = threadIdx.x >> 5;
    int id = blockIdx.x;
    const float* in; bf16* out; int in_ld, out_ld, n0, k0;
    if (id < 3072) {
        const float* Ws[3] = {Wq, Wk, Wv};
        int m = id >> 10, r = id & 1023;
        int z = r >> 6, rt = r & 63;
        in = Ws[m] + z * 65536;                       // [1024][64]
        out = wqkvt + (size_t)(m * 1024 + z * 64) * 1024;
        in_ld = 64; out_ld = 1024;
        n0 = (rt & 1) * 32; k0 = (rt >> 1) * 32;
    } else if (id < 4096) {
        int r = id - 3072;
        in = Wo; out = wot; in_ld = 1024; out_ld = 1024;
        n0 = (r & 31) * 32; k0 = (r >> 5) * 32;
    } else if (id < 8192) {
        int r = id - 4096;
        in = W1; out = w1t; in_ld = 4096; out_ld = 1024;
        n0 = (r & 127) * 32; k0 = (r >> 7) * 32;
    } else {
        int r = id - 8192;
        in = W2; out = w2t; in_ld = 1024; out_ld = 4096;
        n0 = (r & 31) * 32; k0 = (r >> 5) * 32;
    }
#pragma unroll
    for (int i = 0; i < 4; ++i)
        t[ty + i * 8][tx] = in[(size_t)(k0 + ty + i * 8) * in_ld + n0 + tx];
    __syncthreads();
#pragma unroll
    for (int i = 0; i < 4; ++i)
        out[(size_t)(n0 + ty + i * 8) * out_ld + k0 + tx] = f2b(t[tx][ty + i * 8]);
}

// ---------------------------------------------------------------------------
// V^T: vt[(b*16+h)*64 + d][t] = qkv[(b*T+t)*3072 + 2048 + h*64 + d]
// ---------------------------------------------------------------------------
__global__ __launch_bounds__(256) void vt_kernel(
    const bf16* __restrict__ qkv, bf16* __restrict__ vt, int T)
{
    __shared__ float t[32][33];
    int tx = threadIdx.x & 31, ty = threadIdx.x >> 5;
    int z = blockIdx.z, b = z >> 4, h = z & 15;
    const bf16* in = qkv + (size_t)b * T * 3072 + 2048 + h * 64;  // [t][d] ld 3072
    bf16* out = vt + (size_t)z * 64 * T;                          // [d][t] ld T
    int n0 = blockIdx.x * 32, k0 = blockIdx.y * 32;
#pragma unroll
    for (int i = 0; i < 4; ++i)
        t[ty + i * 8][tx] = b2f(in[(size_t)(k0 + ty + i * 8) * 3072 + n0 + tx]);
    __syncthreads();
#pragma unroll
    for (int i = 0; i < 4; ++i)
        out[(size_t)(n0 + ty + i * 8) * T + k0 + tx] = f2b(t[tx][ty + i * 8]);
}

// ---------------------------------------------------------------------------
// MFMA GEMM: C[M,N] = A[M,K] @ B[K,N], B given TRANSPOSED (Bt[n][k]).
// 128x128 tile, BK=32, 256 thr = 4 waves. XOR-swizzled LDS: slot = cb^(row&3)
// applied at the global source address (keeps global_load_lds lane mapping);
// fragment reads become bank-conflict-free.
// ---------------------------------------------------------------------------
template<bool RELU, bool HAS_BIAS, bool HAS_RES, typename ResT, typename OutT>
__global__ __launch_bounds__(256) void gemm_bt(
    const bf16* __restrict__ A, int lda,
    const bf16* __restrict__ Bt, int ldb,
    const float* __restrict__ bias,
    const ResT* __restrict__ res, int ldr,
    OutT* __restrict__ Cm, int ldc,
    int M, int N, int K)
{
    __shared__ short As[128 * 32];
    __shared__ short Bs[128 * 32];
    int tid = threadIdx.x, wv = tid >> 6, ln = tid & 63;
    int bm0 = blockIdx.y * 128, bn0 = blockIdx.x * 128;
    int wm = (wv & 1) * 64, wn = (wv >> 1) * 64;
    int quad = ln >> 4, lane15 = ln & 15;

    f32x4 acc[4][4] = {};

    int srow = ln >> 2;                              // row within 16-row chunk
    int scol = (((ln & 3) ^ (srow & 3)) * 8);        // swizzled source col
    int sw   = (quad ^ (lane15 & 3)) * 8;            // swizzled read slot
    const bf16* Ab = A + (size_t)bm0 * lda;
    const bf16* Bb = Bt + (size_t)bn0 * ldb;

    for (int k0 = 0; k0 < K; k0 += 32) {
#pragma unroll
        for (int i = 0; i < 2; ++i) {
            int ch = wv + i * 4;
            load_lds16(Ab + (size_t)(ch * 16 + srow) * lda + k0 + scol, &As[ch * 16 * 32]);
            load_lds16(Bb + (size_t)(ch * 16 + srow) * ldb + k0 + scol, &Bs[ch * 16 * 32]);
        }
        __syncthreads();
        bf16x8 af[4], bfr[4];
#pragma unroll
        for (int mi = 0; mi < 4; ++mi)
            af[mi] = *(const bf16x8*)&As[(wm + mi * 16 + lane15) * 32 + sw];
#pragma unroll
        for (int ni = 0; ni < 4; ++ni)
            bfr[ni] = *(const bf16x8*)&Bs[(wn + ni * 16 + lane15) * 32 + sw];
#pragma unroll
        for (int mi = 0; mi < 4; ++mi)
#pragma unroll
            for (int ni = 0; ni < 4; ++ni)
                acc[mi][ni] = __builtin_amdgcn_mfma_f32_16x16x32_bf16(
                    af[mi], bfr[ni], acc[mi][ni], 0, 0, 0);
        __syncthreads();
    }

#pragma unroll
    for (int mi = 0; mi < 4; ++mi) {
#pragma unroll
        for (int r = 0; r < 4; ++r) {
            int gm = bm0 + wm + mi * 16 + quad * 4 + r;
#pragma unroll
            for (int ni = 0; ni < 4; ++ni) {
                int gn = bn0 + wn + ni * 16 + lane15;
                float v = acc[mi][ni][r];
                if (HAS_BIAS) v += bias[gn];
                if (HAS_RES)  v += ldf(res + (size_t)gm * ldr + gn);
                if (RELU)     v = fmaxf(v, 0.f);
                stf(Cm + (size_t)gm * ldc + gn, v);
            }
        }
    }
}

// ---------------------------------------------------------------------------
// MFMA causal flash attention, S^T form, 128-row q-tile, 512 thr = 8 waves.
// Q held in registers (wave-private). K/V double-buffered in LDS with
// XOR-swizzled layout (slot = cb ^ (row&7), applied at global source addr);
// prefetch of tile kt+1 issued right after the barrier publishing tile kt.
// ---------------------------------------------------------------------------
__global__ __launch_bounds__(512) void attn_kernel(
    const bf16* __restrict__ qkv, const bf16* __restrict__ vt,
    bf16* __restrict__ o, int T)
{
    const int LDQ = 3072;
    const int PS = 72;   // Ps row stride (shorts): 144 B, 16B-aligned
    int qt = blockIdx.x, h = blockIdx.y, b = blockIdx.z;
    int tid = threadIdx.x, wv = tid >> 6, ln = tid & 63;
    int quad = ln >> 4, lane15 = ln & 15, r7 = lane15 & 7;

    __shared__ short KV[2][2][64 * 64];   // [buf][0=K [key][d], 1=V [d][key]]
    __shared__ short Ps[8][16 * PS];      // per-wave [qrow16][key64]

    int lr = ln >> 3;                     // 0..7: row within 8-row chunk
    int lc = ((ln & 7) ^ lr) * 8;         // swizzled source col offset

    const bf16* kbase = qkv + (size_t)(b * T) * LDQ + 1024 + h * 64;
    const bf16* vbase = vt + (size_t)((b * 16 + h) * 64) * T;

    // ---- stage Q (128 rows x 64) into KV area, read into regs, then free it
    short* Qarea = &KV[0][0][0];
#pragma unroll
    for (int i = 0; i < 2; ++i) {
        int ch = wv * 2 + i;
        load_lds16(qkv + (size_t)(b * T + qt * 128 + ch * 8 + lr) * LDQ + h * 64 + lc,
                   &Qarea[ch * 512]);
    }
    __syncthreads();   // Q staged (vmcnt drained by barrier)
    bf16x8 qf[2];
#pragma unroll
    for (int ks = 0; ks < 2; ++ks)
        qf[ks] = *(const bf16x8*)&Qarea[(wv * 16 + lane15) * 64 + (((ks * 4 + quad) ^ r7) * 8)];
    __syncthreads();   // all Q reads done before K/V overwrite

    f32x4 oacc[4] = {};
    float mrun = -1e30f, lrun = 0.f;
    const float scale = 0.125f;  // 1/sqrt(64)
    int qmin = qt * 128 + wv * 16;
    int ntiles = 2 * qt + 2;

    // prefetch tile 0 into buf 0 (wave wv stages rows wv*8..wv*8+7)
    load_lds16(kbase + (size_t)(0 * 64 + wv * 8 + lr) * LDQ + lc, &KV[0][0][wv * 8 * 64]);
    load_lds16(vbase + (size_t)(wv * 8 + lr) * T + 0 * 64 + lc, &KV[0][1][wv * 8 * 64]);

    for (int kt = 0; kt < ntiles; ++kt) {
        __syncthreads();   // tile kt published (barrier drains vmcnt)
        if (kt + 1 < ntiles) {
            int nb = (kt + 1) & 1;
            load_lds16(kbase + (size_t)((kt + 1) * 64 + wv * 8 + lr) * LDQ + lc,
                       &KV[nb][0][wv * 8 * 64]);
            load_lds16(vbase + (size_t)(wv * 8 + lr) * T + (kt + 1) * 64 + lc,
                       &KV[nb][1][wv * 8 * 64]);
        }
        if (kt * 64 > qmin + 15) continue;   // fully masked for this wave

        const short* Ks = &KV[kt & 1][0][0];
        const short* Vs = &KV[kt & 1][1][0];

        // S^T = K Q^T : sacc[mi] holds S^T[key = mi*16+quad*4+r][q = lane15]
        f32x4 sacc[4] = {};
#pragma unroll
        for (int ks = 0; ks < 2; ++ks) {
            int so = ((ks * 4 + quad) ^ r7) * 8;
#pragma unroll
            for (int mi = 0; mi < 4; ++mi) {
                bf16x8 kf = *(const bf16x8*)&Ks[(mi * 16 + lane15) * 64 + so];
                sacc[mi] = __builtin_amdgcn_mfma_f32_16x16x32_bf16(kf, qf[ks], sacc[mi], 0, 0, 0);
            }
        }

        // causal mask: only tiles containing this wave's diagonal
        if (kt * 64 + 63 > qmin) {
            int ql = qmin + lane15;
#pragma unroll
            for (int mi = 0; mi < 4; ++mi)
#pragma unroll
                for (int r = 0; r < 4; ++r)
                    if (kt * 64 + mi * 16 + quad * 4 + r > ql) sacc[mi][r] = -3e38f;
        }

        // in-lane row max (16 keys/lane), cross-quad reduce
        float mx = sacc[0][0];
#pragma unroll
        for (int mi = 0; mi < 4; ++mi)
#pragma unroll
            for (int r = 0; r < 4; ++r) mx = fmaxf(mx, sacc[mi][r]);
        mx = fmaxf(mx, __shfl_xor(mx, 16, 64));
        mx = fmaxf(mx, __shfl_xor(mx, 32, 64));
        float mn = fmaxf(mrun, mx * scale);
        float alpha = __expf(mrun - mn);
        mrun = mn;

        float psum = 0.f;
#pragma unroll
        for (int mi = 0; mi < 4; ++mi) {
            float p[4];
#pragma unroll
            for (int r = 0; r < 4; ++r) {
                p[r] = __expf(fmaf(sacc[mi][r], scale, -mn));
                psum += p[r];
            }
            short tmp[4];
#pragma unroll
            for (int r = 0; r < 4; ++r) {
                bf16 pb = f2b(p[r]);
                tmp[r] = *(short*)&pb;
            }
            *(s16x4*)&Ps[wv][lane15 * PS + mi * 16 + quad * 4] = *(s16x4*)tmp;
        }
        lrun = lrun * alpha + psum;
#pragma unroll
        for (int di = 0; di < 4; ++di)
#pragma unroll
            for (int r = 0; r < 4; ++r) oacc[di][r] *= alpha;

        // O^T += V^T P^T  (wave-private Ps: no barrier needed)
#pragma unroll
        for (int ks = 0; ks < 2; ++ks) {
            int so = ((ks * 4 + quad) ^ r7) * 8;
            bf16x8 pf = *(const bf16x8*)&Ps[wv][lane15 * PS + ks * 32 + quad * 8];
#pragma unroll
            for (int di = 0; di < 4; ++di) {
                bf16x8 vf = *(const bf16x8*)&Vs[(di * 16 + lane15) * 64 + so];
                oacc[di] = __builtin_amdgcn_mfma_f32_16x16x32_bf16(vf, pf, oacc[di], 0, 0, 0);
            }
        }
    }

    // full row l: sum partials across the 4 quads
    lrun += __shfl_xor(lrun, 16, 64);
    lrun += __shfl_xor(lrun, 32, 64);
    float inv = 1.f / lrun;

    size_t row = (size_t)(b * T + qt * 128 + wv * 16 + lane15);
#pragma unroll
    for (int di = 0; di < 4; ++di) {
        short tmp[4];
#pragma unroll
        for (int r = 0; r < 4; ++r) {
            bf16 ob = f2b(oacc[di][r] * inv);
            tmp[r] = *(short*)&ob;
        }
        *(s16x4*)&o[row * 1024 + h * 64 + di * 16 + quad * 4] = *(s16x4*)tmp;
    }
}

// ---------------------------------------------------------------------------
extern "C" void kernel_launch(void* const* d_in, const int* in_sizes, int n_in,
                              void* d_out, int out_size, void* d_ws, size_t ws_size,
                              hipStream_t stream)
{
    (void)in_sizes; (void)n_in; (void)out_size; (void)ws_size;
    const float* x   = (const float*)d_in[0];
    const float* Wq  = (const float*)d_in[1];
    const float* Wk  = (const float*)d_in[2];
    const float* Wv  = (const float*)d_in[3];
    const float* Wo  = (const float*)d_in[4];
    const float* bo  = (const float*)d_in[5];
    const float* g1  = (const float*)d_in[6];
    const float* be1 = (const float*)d_in[7];
    const float* g2  = (const float*)d_in[8];
    const float* be2 = (const float*)d_in[9];
    const float* W1  = (const float*)d_in[10];
    const float* b1  = (const float*)d_in[11];
    const float* W2  = (const float*)d_in[12];
    const float* b2  = (const float*)d_in[13];

    const int T = 2048, M = 4 * T;  // 8192 rows
    const size_t MB = 1ull << 20;
    char* ws = (char*)d_ws;

    // workspace map (128 MB, live-range overlays):
    bf16*  xn    = (bf16*)(ws + 0 * MB);     // 16 MB; later: attnb; later: hb
    bf16*  qkv   = (bf16*)(ws + 16 * MB);    // 48 MB [M][3072]; later: hb tail
    bf16*  vt    = (bf16*)(ws + 64 * MB);    // 16 MB [b*16+h][64][T]
    bf16*  wqkvt = (bf16*)(ws + 80 * MB);    //  6 MB [3072][1024]; later: x1b
    bf16*  x1b   = (bf16*)(ws + 80 * MB);    // 16 MB [M][1024] bf16 residual
    bf16*  wot   = (bf16*)(ws + 96 * MB);    //  2 MB; later: xn2
    bf16*  xn2   = (bf16*)(ws + 96 * MB);    // 16 MB
    bf16*  w1t   = (bf16*)(ws + 112 * MB);   //  8 MB [4096][1024]
    bf16*  w2t   = (bf16*)(ws + 120 * MB);   //  8 MB [1024][4096]
    bf16*  attnb = (bf16*)(ws + 0 * MB);
    bf16*  hb    = (bf16*)(ws + 0 * MB);     // 64 MB [M][4096]

    dim3 blk(256);

    prep_weights<<<12288, blk, 0, stream>>>(Wq, Wk, Wv, Wo, W1, W2,
                                            wqkvt, wot, w1t, w2t);

    ln_kernel<float><<<M, blk, 0, stream>>>(x, g1, be1, xn);

    gemm_bt<false, false, false, float, bf16><<<dim3(24, 64), blk, 0, stream>>>(
        xn, 1024, wqkvt, 1024, nullptr, nullptr, 0, qkv, 3072, M, 3072, 1024);

    vt_kernel<<<dim3(2, T / 32, 64), blk, 0, stream>>>(qkv, vt, T);

    attn_kernel<<<dim3(T / 128, 16, 4), dim3(512), 0, stream>>>(qkv, vt, attnb, T);

    gemm_bt<false, true, true, float, bf16><<<dim3(8, 64), blk, 0, stream>>>(
        attnb, 1024, wot, 1024, bo, x, 1024, x1b, 1024, M, 1024, 1024);

    ln_kernel<bf16><<<M, blk, 0, stream>>>(x1b, g2, be2, xn2);

    gemm_bt<true, true, false, float, bf16><<<dim3(32, 64), blk, 0, stream>>>(
        xn2, 1024, w1t, 1024, b1, nullptr, 0, hb, 4096, M, 4096, 1024);

    gemm_bt<false, true, true, bf16, float><<<dim3(8, 64), blk, 0, stream>>>(
        hb, 4096, w2t, 4096, b2, x1b, 1024, (float*)d_out, 1024, M, 1024, 4096);
}

// Round 7
// 564.193 us; speedup vs baseline: 12.3336x; 1.0391x over previous
//
#include <hip/hip_runtime.h>
#include <hip/hip_bf16.h>

typedef __hip_bfloat16 bf16;
typedef __attribute__((ext_vector_type(8))) short bf16x8;
typedef __attribute__((ext_vector_type(4))) short s16x4;
typedef __attribute__((ext_vector_type(4))) float f32x4;

__device__ __forceinline__ float b2f(bf16 v) { return __bfloat162float(v); }
__device__ __forceinline__ bf16  f2b(float v) { return __float2bfloat16(v); }
__device__ __forceinline__ float ldf(const bf16* p)  { return __bfloat162float(*p); }
__device__ __forceinline__ float ldf(const float* p) { return *p; }
__device__ __forceinline__ void  stf(bf16* p, float v)  { *p = __float2bfloat16(v); }
__device__ __forceinline__ void  stf(float* p, float v) { *p = v; }

// async global->LDS, 16 B per lane; LDS dest = wave-uniform base + lane*16
__device__ __forceinline__ void load_lds16(const bf16* g, short* lds) {
    __builtin_amdgcn_global_load_lds(
        (const __attribute__((address_space(1))) unsigned int*)g,
        (__attribute__((address_space(3))) unsigned int*)lds, 16, 0, 0);
}

// ---------------------------------------------------------------------------
// LayerNorm over last dim C=1024. One block (256 threads) per row. bf16 out.
// ---------------------------------------------------------------------------
template<typename InT>
__global__ __launch_bounds__(256) void ln_kernel(const InT* __restrict__ x,
                                                 const float* __restrict__ g,
                                                 const float* __restrict__ b,
                                                 bf16* __restrict__ out)
{
    const int C = 1024;
    int row = blockIdx.x;
    int tid = threadIdx.x;
    const InT* xr = x + (size_t)row * C;

    float v[4];
    float s = 0.f, s2 = 0.f;
#pragma unroll
    for (int i = 0; i < 4; ++i) {
        float f = ldf(xr + tid + i * 256);
        v[i] = f; s += f; s2 += f * f;
    }
#pragma unroll
    for (int off = 32; off > 0; off >>= 1) {
        s  += __shfl_down(s,  off, 64);
        s2 += __shfl_down(s2, off, 64);
    }
    __shared__ float red[8];
    int wave = tid >> 6;
    if ((tid & 63) == 0) { red[wave] = s; red[wave + 4] = s2; }
    __syncthreads();
    float ts  = red[0] + red[1] + red[2] + red[3];
    float ts2 = red[4] + red[5] + red[6] + red[7];
    float mu  = ts * (1.f / 1024.f);
    float var = ts2 * (1.f / 1024.f) - mu * mu;
    float rstd = rsqrtf(var + 1e-5f);
#pragma unroll
    for (int i = 0; i < 4; ++i) {
        int c = tid + i * 256;
        out[(size_t)row * C + c] = f2b((v[i] - mu) * rstd * g[c] + b[c]);
    }
}

// ---------------------------------------------------------------------------
// All six weight transposes (fp32 -> bf16, out[n][k] = in[k][n]) in ONE
// kernel. Flat tile id selects matrix + 32x32 tile.
// ---------------------------------------------------------------------------
__global__ __launch_bounds__(256) void prep_weights(
    const float* __restrict__ Wq, const float* __restrict__ Wk,
    const float* __restrict__ Wv, const float* __restrict__ Wo,
    const float* __restrict__ W1, const float* __restrict__ W2,
    bf16* __restrict__ wqkvt, bf16* __restrict__ wot,
    bf16* __restrict__ w1t, bf16* __restrict__ w2t)
{
    __shared__ float t[32][33];
    int tx = threadIdx.x & 31, ty = threadIdx.x >> 5;
    int id = blockIdx.x;
    const float* in; bf16* out; int in_ld, out_ld, n0, k0;
    if (id < 3072) {
        const float* Ws[3] = {Wq, Wk, Wv};
        int m = id >> 10, r = id & 1023;
        int z = r >> 6, rt = r & 63;
        in = Ws[m] + z * 65536;                       // [1024][64]
        out = wqkvt + (size_t)(m * 1024 + z * 64) * 1024;
        in_ld = 64; out_ld = 1024;
        n0 = (rt & 1) * 32; k0 = (rt >> 1) * 32;
    } else if (id < 4096) {
        int r = id - 3072;
        in = Wo; out = wot; in_ld = 1024; out_ld = 1024;
        n0 = (r & 31) * 32; k0 = (r >> 5) * 32;
    } else if (id < 8192) {
        int r = id - 4096;
        in = W1; out = w1t; in_ld = 4096; out_ld = 1024;
        n0 = (r & 127) * 32; k0 = (r >> 7) * 32;
    } else {
        int r = id - 8192;
        in = W2; out = w2t; in_ld = 1024; out_ld = 4096;
        n0 = (r & 31) * 32; k0 = (r >> 5) * 32;
    }
#pragma unroll
    for (int i = 0; i < 4; ++i)
        t[ty + i * 8][tx] = in[(size_t)(k0 + ty + i * 8) * in_ld + n0 + tx];
    __syncthreads();
#pragma unroll
    for (int i = 0; i < 4; ++i)
        out[(size_t)(n0 + ty + i * 8) * out_ld + k0 + tx] = f2b(t[tx][ty + i * 8]);
}

// ---------------------------------------------------------------------------
// V^T: vt[(b*16+h)*64 + d][t] = qkv[(b*T+t)*3072 + 2048 + h*64 + d]
// ---------------------------------------------------------------------------
__global__ __launch_bounds__(256) void vt_kernel(
    const bf16* __restrict__ qkv, bf16* __restrict__ vt, int T)
{
    __shared__ float t[32][33];
    int tx = threadIdx.x & 31, ty = threadIdx.x >> 5;
    int z = blockIdx.z, b = z >> 4, h = z & 15;
    const bf16* in = qkv + (size_t)b * T * 3072 + 2048 + h * 64;  // [t][d] ld 3072
    bf16* out = vt + (size_t)z * 64 * T;                          // [d][t] ld T
    int n0 = blockIdx.x * 32, k0 = blockIdx.y * 32;
#pragma unroll
    for (int i = 0; i < 4; ++i)
        t[ty + i * 8][tx] = b2f(in[(size_t)(k0 + ty + i * 8) * 3072 + n0 + tx]);
    __syncthreads();
#pragma unroll
    for (int i = 0; i < 4; ++i)
        out[(size_t)(n0 + ty + i * 8) * T + k0 + tx] = f2b(t[tx][ty + i * 8]);
}

// ---------------------------------------------------------------------------
// MFMA GEMM: C[M,N] = A[M,K] @ B[K,N], B given TRANSPOSED (Bt[n][k]).
// 128x128 tile, BK=32, 256 thr = 4 waves. XOR-swizzled LDS fragments.
// XCD-aware block remap: flat id -> (by = f % nby, bx = f / nby). With
// nby % 8 == 0, all col-blocks sharing an A row-tile satisfy f % 8 == by % 8
// -> same XCD -> A-tile fetched once per XCD L2 instead of once per XCD
// per col-block.
// ---------------------------------------------------------------------------
template<bool RELU, bool HAS_BIAS, bool HAS_RES, typename ResT, typename OutT>
__global__ __launch_bounds__(256) void gemm_bt(
    const bf16* __restrict__ A, int lda,
    const bf16* __restrict__ Bt, int ldb,
    const float* __restrict__ bias,
    const ResT* __restrict__ res, int ldr,
    OutT* __restrict__ Cm, int ldc,
    int M, int N, int K)
{
    __shared__ short As[128 * 32];
    __shared__ short Bs[128 * 32];
    int tid = threadIdx.x, wv = tid >> 6, ln = tid & 63;

    // XCD-locality remap (see header comment)
    int f = blockIdx.x + blockIdx.y * gridDim.x;
    int nby = gridDim.y;
    int by = f % nby, bx = f / nby;
    int bm0 = by * 128, bn0 = bx * 128;

    int wm = (wv & 1) * 64, wn = (wv >> 1) * 64;
    int quad = ln >> 4, lane15 = ln & 15;

    f32x4 acc[4][4] = {};

    int srow = ln >> 2;                              // row within 16-row chunk
    int scol = (((ln & 3) ^ (srow & 3)) * 8);        // swizzled source col
    int sw   = (quad ^ (lane15 & 3)) * 8;            // swizzled read slot
    const bf16* Ab = A + (size_t)bm0 * lda;
    const bf16* Bb = Bt + (size_t)bn0 * ldb;

    for (int k0 = 0; k0 < K; k0 += 32) {
#pragma unroll
        for (int i = 0; i < 2; ++i) {
            int ch = wv + i * 4;
            load_lds16(Ab + (size_t)(ch * 16 + srow) * lda + k0 + scol, &As[ch * 16 * 32]);
            load_lds16(Bb + (size_t)(ch * 16 + srow) * ldb + k0 + scol, &Bs[ch * 16 * 32]);
        }
        __syncthreads();
        bf16x8 af[4], bfr[4];
#pragma unroll
        for (int mi = 0; mi < 4; ++mi)
            af[mi] = *(const bf16x8*)&As[(wm + mi * 16 + lane15) * 32 + sw];
#pragma unroll
        for (int ni = 0; ni < 4; ++ni)
            bfr[ni] = *(const bf16x8*)&Bs[(wn + ni * 16 + lane15) * 32 + sw];
#pragma unroll
        for (int mi = 0; mi < 4; ++mi)
#pragma unroll
            for (int ni = 0; ni < 4; ++ni)
                acc[mi][ni] = __builtin_amdgcn_mfma_f32_16x16x32_bf16(
                    af[mi], bfr[ni], acc[mi][ni], 0, 0, 0);
        __syncthreads();
    }

#pragma unroll
    for (int mi = 0; mi < 4; ++mi) {
#pragma unroll
        for (int r = 0; r < 4; ++r) {
            int gm = bm0 + wm + mi * 16 + quad * 4 + r;
#pragma unroll
            for (int ni = 0; ni < 4; ++ni) {
                int gn = bn0 + wn + ni * 16 + lane15;
                float v = acc[mi][ni][r];
                if (HAS_BIAS) v += bias[gn];
                if (HAS_RES)  v += ldf(res + (size_t)gm * ldr + gn);
                if (RELU)     v = fmaxf(v, 0.f);
                stf(Cm + (size_t)gm * ldc + gn, v);
            }
        }
    }
}

// ---------------------------------------------------------------------------
// MFMA causal flash attention, S^T form, 128-row q-tile, 512 thr = 8 waves.
// Q held in registers (wave-private). K/V double-buffered in LDS with
// XOR-swizzled layout; prefetch of tile kt+1 issued right after the barrier
// publishing tile kt.
// ---------------------------------------------------------------------------
__global__ __launch_bounds__(512) void attn_kernel(
    const bf16* __restrict__ qkv, const bf16* __restrict__ vt,
    bf16* __restrict__ o, int T)
{
    const int LDQ = 3072;
    const int PS = 72;   // Ps row stride (shorts): 144 B, 16B-aligned
    int qt = blockIdx.x, h = blockIdx.y, b = blockIdx.z;
    int tid = threadIdx.x, wv = tid >> 6, ln = tid & 63;
    int quad = ln >> 4, lane15 = ln & 15, r7 = lane15 & 7;

    __shared__ short KV[2][2][64 * 64];   // [buf][0=K [key][d], 1=V [d][key]]
    __shared__ short Ps[8][16 * PS];      // per-wave [qrow16][key64]

    int lr = ln >> 3;                     // 0..7: row within 8-row chunk
    int lc = ((ln & 7) ^ lr) * 8;         // swizzled source col offset

    const bf16* kbase = qkv + (size_t)(b * T) * LDQ + 1024 + h * 64;
    const bf16* vbase = vt + (size_t)((b * 16 + h) * 64) * T;

    // ---- stage Q (128 rows x 64) into KV area, read into regs, then free it
    short* Qarea = &KV[0][0][0];
#pragma unroll
    for (int i = 0; i < 2; ++i) {
        int ch = wv * 2 + i;
        load_lds16(qkv + (size_t)(b * T + qt * 128 + ch * 8 + lr) * LDQ + h * 64 + lc,
                   &Qarea[ch * 512]);
    }
    __syncthreads();   // Q staged (vmcnt drained by barrier)
    bf16x8 qf[2];
#pragma unroll
    for (int ks = 0; ks < 2; ++ks)
        qf[ks] = *(const bf16x8*)&Qarea[(wv * 16 + lane15) * 64 + (((ks * 4 + quad) ^ r7) * 8)];
    __syncthreads();   // all Q reads done before K/V overwrite

    f32x4 oacc[4] = {};
    float mrun = -1e30f, lrun = 0.f;
    const float scale = 0.125f;  // 1/sqrt(64)
    int qmin = qt * 128 + wv * 16;
    int ntiles = 2 * qt + 2;

    // prefetch tile 0 into buf 0 (wave wv stages rows wv*8..wv*8+7)
    load_lds16(kbase + (size_t)(0 * 64 + wv * 8 + lr) * LDQ + lc, &KV[0][0][wv * 8 * 64]);
    load_lds16(vbase + (size_t)(wv * 8 + lr) * T + 0 * 64 + lc, &KV[0][1][wv * 8 * 64]);

    for (int kt = 0; kt < ntiles; ++kt) {
        __syncthreads();   // tile kt published (barrier drains vmcnt)
        if (kt + 1 < ntiles) {
            int nb = (kt + 1) & 1;
            load_lds16(kbase + (size_t)((kt + 1) * 64 + wv * 8 + lr) * LDQ + lc,
                       &KV[nb][0][wv * 8 * 64]);
            load_lds16(vbase + (size_t)(wv * 8 + lr) * T + (kt + 1) * 64 + lc,
                       &KV[nb][1][wv * 8 * 64]);
        }
        if (kt * 64 > qmin + 15) continue;   // fully masked for this wave

        const short* Ks = &KV[kt & 1][0][0];
        const short* Vs = &KV[kt & 1][1][0];

        // S^T = K Q^T : sacc[mi] holds S^T[key = mi*16+quad*4+r][q = lane15]
        f32x4 sacc[4] = {};
#pragma unroll
        for (int ks = 0; ks < 2; ++ks) {
            int so = ((ks * 4 + quad) ^ r7) * 8;
#pragma unroll
            for (int mi = 0; mi < 4; ++mi) {
                bf16x8 kf = *(const bf16x8*)&Ks[(mi * 16 + lane15) * 64 + so];
                sacc[mi] = __builtin_amdgcn_mfma_f32_16x16x32_bf16(kf, qf[ks], sacc[mi], 0, 0, 0);
            }
        }

        // causal mask: only tiles containing this wave's diagonal
        if (kt * 64 + 63 > qmin) {
            int ql = qmin + lane15;
#pragma unroll
            for (int mi = 0; mi < 4; ++mi)
#pragma unroll
                for (int r = 0; r < 4; ++r)
                    if (kt * 64 + mi * 16 + quad * 4 + r > ql) sacc[mi][r] = -3e38f;
        }

        // in-lane row max (16 keys/lane), cross-quad reduce
        float mx = sacc[0][0];
#pragma unroll
        for (int mi = 0; mi < 4; ++mi)
#pragma unroll
            for (int r = 0; r < 4; ++r) mx = fmaxf(mx, sacc[mi][r]);
        mx = fmaxf(mx, __shfl_xor(mx, 16, 64));
        mx = fmaxf(mx, __shfl_xor(mx, 32, 64));
        float mn = fmaxf(mrun, mx * scale);
        float alpha = __expf(mrun - mn);
        mrun = mn;

        float psum = 0.f;
#pragma unroll
        for (int mi = 0; mi < 4; ++mi) {
            float p[4];
#pragma unroll
            for (int r = 0; r < 4; ++r) {
                p[r] = __expf(fmaf(sacc[mi][r], scale, -mn));
                psum += p[r];
            }
            short tmp[4];
#pragma unroll
            for (int r = 0; r < 4; ++r) {
                bf16 pb = f2b(p[r]);
                tmp[r] = *(short*)&pb;
            }
            *(s16x4*)&Ps[wv][lane15 * PS + mi * 16 + quad * 4] = *(s16x4*)tmp;
        }
        lrun = lrun * alpha + psum;
#pragma unroll
        for (int di = 0; di < 4; ++di)
#pragma unroll
            for (int r = 0; r < 4; ++r) oacc[di][r] *= alpha;

        // O^T += V^T P^T  (wave-private Ps: no barrier needed)
#pragma unroll
        for (int ks = 0; ks < 2; ++ks) {
            int so = ((ks * 4 + quad) ^ r7) * 8;
            bf16x8 pf = *(const bf16x8*)&Ps[wv][lane15 * PS + ks * 32 + quad * 8];
#pragma unroll
            for (int di = 0; di < 4; ++di) {
                bf16x8 vf = *(const bf16x8*)&Vs[(di * 16 + lane15) * 64 + so];
                oacc[di] = __builtin_amdgcn_mfma_f32_16x16x32_bf16(vf, pf, oacc[di], 0, 0, 0);
            }
        }
    }

    // full row l: sum partials across the 4 quads
    lrun += __shfl_xor(lrun, 16, 64);
    lrun += __shfl_xor(lrun, 32, 64);
    float inv = 1.f / lrun;

    size_t row = (size_t)(b * T + qt * 128 + wv * 16 + lane15);
#pragma unroll
    for (int di = 0; di < 4; ++di) {
        short tmp[4];
#pragma unroll
        for (int r = 0; r < 4; ++r) {
            bf16 ob = f2b(oacc[di][r] * inv);
            tmp[r] = *(short*)&ob;
        }
        *(s16x4*)&o[row * 1024 + h * 64 + di * 16 + quad * 4] = *(s16x4*)tmp;
    }
}

// ---------------------------------------------------------------------------
extern "C" void kernel_launch(void* const* d_in, const int* in_sizes, int n_in,
                              void* d_out, int out_size, void* d_ws, size_t ws_size,
                              hipStream_t stream)
{
    (void)in_sizes; (void)n_in; (void)out_size; (void)ws_size;
    const float* x   = (const float*)d_in[0];
    const float* Wq  = (const float*)d_in[1];
    const float* Wk  = (const float*)d_in[2];
    const float* Wv  = (const float*)d_in[3];
    const float* Wo  = (const float*)d_in[4];
    const float* bo  = (const float*)d_in[5];
    const float* g1  = (const float*)d_in[6];
    const float* be1 = (const float*)d_in[7];
    const float* g2  = (const float*)d_in[8];
    const float* be2 = (const float*)d_in[9];
    const float* W1  = (const float*)d_in[10];
    const float* b1  = (const float*)d_in[11];
    const float* W2  = (const float*)d_in[12];
    const float* b2  = (const float*)d_in[13];

    const int T = 2048, M = 4 * T;  // 8192 rows
    const size_t MB = 1ull << 20;
    char* ws = (char*)d_ws;

    // workspace map (128 MB, live-range overlays):
    bf16*  xn    = (bf16*)(ws + 0 * MB);     // 16 MB; later: attnb; later: hb
    bf16*  qkv   = (bf16*)(ws + 16 * MB);    // 48 MB [M][3072]; later: hb tail
    bf16*  vt    = (bf16*)(ws + 64 * MB);    // 16 MB [b*16+h][64][T]
    bf16*  wqkvt = (bf16*)(ws + 80 * MB);    //  6 MB [3072][1024]; later: x1b
    bf16*  x1b   = (bf16*)(ws + 80 * MB);    // 16 MB [M][1024] bf16 residual
    bf16*  wot   = (bf16*)(ws + 96 * MB);    //  2 MB; later: xn2
    bf16*  xn2   = (bf16*)(ws + 96 * MB);    // 16 MB
    bf16*  w1t   = (bf16*)(ws + 112 * MB);   //  8 MB [4096][1024]
    bf16*  w2t   = (bf16*)(ws + 120 * MB);   //  8 MB [1024][4096]
    bf16*  attnb = (bf16*)(ws + 0 * MB);
    bf16*  hb    = (bf16*)(ws + 0 * MB);     // 64 MB [M][4096]

    dim3 blk(256);

    prep_weights<<<12288, blk, 0, stream>>>(Wq, Wk, Wv, Wo, W1, W2,
                                            wqkvt, wot, w1t, w2t);

    ln_kernel<float><<<M, blk, 0, stream>>>(x, g1, be1, xn);

    gemm_bt<false, false, false, float, bf16><<<dim3(24, 64), blk, 0, stream>>>(
        xn, 1024, wqkvt, 1024, nullptr, nullptr, 0, qkv, 3072, M, 3072, 1024);

    vt_kernel<<<dim3(2, T / 32, 64), blk, 0, stream>>>(qkv, vt, T);

    attn_kernel<<<dim3(T / 128, 16, 4), dim3(512), 0, stream>>>(qkv, vt, attnb, T);

    gemm_bt<false, true, true, float, bf16><<<dim3(8, 64), blk, 0, stream>>>(
        attnb, 1024, wot, 1024, bo, x, 1024, x1b, 1024, M, 1024, 1024);

    ln_kernel<bf16><<<M, blk, 0, stream>>>(x1b, g2, be2, xn2);

    gemm_bt<true, true, false, float, bf16><<<dim3(32, 64), blk, 0, stream>>>(
        xn2, 1024, w1t, 1024, b1, nullptr, 0, hb, 4096, M, 4096, 1024);

    gemm_bt<false, true, true, bf16, float><<<dim3(8, 64), blk, 0, stream>>>(
        hb, 4096, w2t, 4096, b2, x1b, 1024, (float*)d_out, 1024, M, 1024, 4096);
}